// Round 1
// baseline (2103.355 us; speedup 1.0000x reference)
//
#include <hip/hip_runtime.h>
#include <float.h>
#include <math.h>

// Problem constants (KNNAttention: b=4, l=2048, d=1024, h=16, dh=64, n_mem=1000)
#define BATCH 4
#define SEQ   2048
#define DIM   1024
#define NHEAD 16
#define DHEAD 64
#define NMEM  1000
#define ROWS  (BATCH*SEQ)   // 8192

typedef __attribute__((ext_vector_type(8))) __bf16 bf16x8;
typedef __attribute__((ext_vector_type(4))) float  f32x4;

static __device__ inline f32x4 mfma16(bf16x8 a, bf16x8 b, f32x4 c) {
  return __builtin_amdgcn_mfma_f32_16x16x32_bf16(a, b, c, 0, 0, 0);
}

// ---------------------------------------------------------------------------
// Generic f32 GEMM: C = A(MxK) @ B(KxN), all row-major. Tile 128x64, 8x4/thread.
// ---------------------------------------------------------------------------
__global__ __launch_bounds__(256) void gemm_f32(const float* __restrict__ A,
                                                const float* __restrict__ B,
                                                float* __restrict__ C,
                                                int M, int N, int K) {
  __shared__ float As[16][132];  // [k][row] transposed, padded
  __shared__ float Bs[16][68];   // [k][col], padded
  const int t = threadIdx.x;
  const int tx = t & 15, ty = t >> 4;
  const int m0 = blockIdx.x * 128, n0 = blockIdx.y * 64;
  float acc[8][4] = {};

  for (int k0 = 0; k0 < K; k0 += 16) {
    #pragma unroll
    for (int i = 0; i < 8; ++i) {           // stage A: 128x16 -> As[k][row]
      int e = t + 256 * i;
      int r = e >> 4, c = e & 15;
      As[c][r] = A[(size_t)(m0 + r) * K + k0 + c];
    }
    #pragma unroll
    for (int i = 0; i < 4; ++i) {           // stage B: 16x64
      int e = t + 256 * i;
      int r = e >> 6, c = e & 63;
      Bs[r][c] = B[(size_t)(k0 + r) * N + n0 + c];
    }
    __syncthreads();
    #pragma unroll
    for (int k = 0; k < 16; ++k) {
      float4 a0 = *(const float4*)&As[k][ty * 8];
      float4 a1 = *(const float4*)&As[k][ty * 8 + 4];
      float4 bv = *(const float4*)&Bs[k][tx * 4];
      float av[8] = {a0.x, a0.y, a0.z, a0.w, a1.x, a1.y, a1.z, a1.w};
      float bb[4] = {bv.x, bv.y, bv.z, bv.w};
      #pragma unroll
      for (int i = 0; i < 8; ++i)
        #pragma unroll
        for (int j = 0; j < 4; ++j)
          acc[i][j] = fmaf(av[i], bb[j], acc[i][j]);
    }
    __syncthreads();
  }
  #pragma unroll
  for (int i = 0; i < 8; ++i)
    #pragma unroll
    for (int j = 0; j < 4; ++j)
      C[(size_t)(m0 + ty * 8 + i) * N + n0 + tx * 4 + j] = acc[i][j];
}

// ---------------------------------------------------------------------------
// kNN scores + partial argmax. Block: 64 query rows x 256-mem chunk.
// grid = (ROWS/64, 4 chunks). f32 for argmax robustness.
// ---------------------------------------------------------------------------
__global__ __launch_bounds__(256) void knn_partial(const float* __restrict__ qp,
                                                   const float* __restrict__ mem,
                                                   float* __restrict__ pv,
                                                   int* __restrict__ pi) {
  __shared__ float As[64][68];   // qp tile, [k][row]
  __shared__ float Ms[64][68];   // mem tile, [k][n]
  const int t = threadIdx.x;
  const int tx = t & 15, ty = t >> 4;
  const int m0 = blockIdx.x * 64;
  const int batch = m0 >> 11;   // 2048 rows per batch

  float bestv[4];
  int   besti[4];
  #pragma unroll
  for (int r = 0; r < 4; ++r) { bestv[r] = -FLT_MAX; besti[r] = 0; }

  for (int nt = 0; nt < 4; ++nt) {
    const int n0 = blockIdx.y * 256 + nt * 64;
    float acc[4][4] = {};
    for (int k0 = 0; k0 < DIM; k0 += 64) {
      #pragma unroll
      for (int i = 0; i < 16; ++i) {
        int e = t + 256 * i;
        int r = e >> 6, c = e & 63;
        As[c][r] = qp[(size_t)(m0 + r) * DIM + k0 + c];
        int n = n0 + r;
        Ms[c][r] = (n < NMEM) ? mem[((size_t)batch * NMEM + n) * DIM + k0 + c] : 0.f;
      }
      __syncthreads();
      #pragma unroll
      for (int k = 0; k < 64; ++k) {
        float4 av = *(const float4*)&As[k][ty * 4];
        float4 mv = *(const float4*)&Ms[k][tx * 4];
        float aa[4] = {av.x, av.y, av.z, av.w};
        float mm[4] = {mv.x, mv.y, mv.z, mv.w};
        #pragma unroll
        for (int i = 0; i < 4; ++i)
          #pragma unroll
          for (int j = 0; j < 4; ++j)
            acc[i][j] = fmaf(aa[i], mm[j], acc[i][j]);
      }
      __syncthreads();
    }
    // per-row argmax over this 64-col tile (first-max tie-break: lowest idx)
    #pragma unroll
    for (int r = 0; r < 4; ++r) {
      float v = -FLT_MAX; int vi = 0x7fffffff;
      #pragma unroll
      for (int j = 0; j < 4; ++j) {
        int n = n0 + tx * 4 + j;
        float s = (n < NMEM) ? acc[r][j] : -FLT_MAX;
        if (s > v) { v = s; vi = n; }
      }
      #pragma unroll
      for (int off = 1; off < 16; off <<= 1) {
        float ov = __shfl_xor(v, off);
        int   oi = __shfl_xor(vi, off);
        if (ov > v || (ov == v && oi < vi)) { v = ov; vi = oi; }
      }
      if (v > bestv[r] || (v == bestv[r] && vi < besti[r])) { bestv[r] = v; besti[r] = vi; }
    }
  }
  if (tx == 0) {
    #pragma unroll
    for (int r = 0; r < 4; ++r) {
      int row = m0 + ty * 4 + r;
      pv[(size_t)blockIdx.y * ROWS + row] = bestv[r];
      pi[(size_t)blockIdx.y * ROWS + row] = besti[r];
    }
  }
}

__global__ void knn_reduce(const float* __restrict__ pv, const int* __restrict__ pi,
                           int* __restrict__ idx) {
  int r = blockIdx.x * 256 + threadIdx.x;
  if (r >= ROWS) return;
  float bv = -FLT_MAX; int bi = 0x7fffffff;
  #pragma unroll
  for (int c = 0; c < 4; ++c) {
    float v = pv[(size_t)c * ROWS + r];
    int i = pi[(size_t)c * ROWS + r];
    if (v > bv || (v == bv && i < bi)) { bv = v; bi = i; }
  }
  idx[r] = bi;
}

// ---------------------------------------------------------------------------
// Gather mem[idx] and compute @ w_kv -> k,v written as bf16 (b, l, 64) each.
// Block: 64 rows, full N=128. grid = ROWS/64.
// ---------------------------------------------------------------------------
__global__ __launch_bounds__(256) void kv_gemm(const float* __restrict__ mem,
                                               const int* __restrict__ idx,
                                               const float* __restrict__ w_kv,
                                               __bf16* __restrict__ kbf,
                                               __bf16* __restrict__ vbf) {
  __shared__ float As[16][68];    // gathered mem tile [k][row]
  __shared__ float Bs[16][128];   // w_kv tile [k][col]
  __shared__ int sidx[64];
  const int t = threadIdx.x;
  const int m0 = blockIdx.x * 64;
  const int batch = m0 >> 11;
  if (t < 64) sidx[t] = idx[m0 + t];
  __syncthreads();
  const int tx = t & 31, ty = t >> 5;   // cols 4*tx (128), rows 8*ty (64)
  float acc[8][4] = {};

  for (int k0 = 0; k0 < DIM; k0 += 16) {
    #pragma unroll
    for (int i = 0; i < 4; ++i) {       // 64x16 gathered A
      int e = t + 256 * i;
      int r = e >> 4, c = e & 15;
      As[c][r] = mem[((size_t)batch * NMEM + sidx[r]) * DIM + k0 + c];
    }
    #pragma unroll
    for (int i = 0; i < 8; ++i) {       // 16x128 B
      int e = t + 256 * i;
      int r = e >> 7, c = e & 127;
      Bs[r][c] = w_kv[(size_t)(k0 + r) * 128 + c];
    }
    __syncthreads();
    #pragma unroll
    for (int k = 0; k < 16; ++k) {
      float4 a0 = *(const float4*)&As[k][ty * 8];
      float4 a1 = *(const float4*)&As[k][ty * 8 + 4];
      float4 bv = *(const float4*)&Bs[k][tx * 4];
      float av[8] = {a0.x, a0.y, a0.z, a0.w, a1.x, a1.y, a1.z, a1.w};
      float bb[4] = {bv.x, bv.y, bv.z, bv.w};
      #pragma unroll
      for (int i = 0; i < 8; ++i)
        #pragma unroll
        for (int j = 0; j < 4; ++j)
          acc[i][j] = fmaf(av[i], bb[j], acc[i][j]);
    }
    __syncthreads();
  }
  #pragma unroll
  for (int i = 0; i < 8; ++i) {
    int row = m0 + ty * 8 + i;
    #pragma unroll
    for (int j = 0; j < 4; ++j) {
      int col = tx * 4 + j;
      __bf16 hv = (__bf16)acc[i][j];
      if (col < DHEAD) kbf[(size_t)row * DHEAD + col] = hv;
      else             vbf[(size_t)row * DHEAD + (col - DHEAD)] = hv;
    }
  }
}

// ---------------------------------------------------------------------------
// Flash attention, bf16 MFMA 16x16x32. Block: 4 waves x 16 q-rows = 64 rows of
// one (b,h). K/V shared across heads (served from L2). grid = (32, 16, 4).
// ---------------------------------------------------------------------------
__global__ __launch_bounds__(256) void flash_attn(const float* __restrict__ qp,
                                                  const __bf16* __restrict__ kbf,
                                                  const __bf16* __restrict__ vbf,
                                                  float* __restrict__ attn_out) {
  // Padded LDS strides (bytes): Kt rows 144, Vt rows 80, Pt rows 80 -> conflict-light
  __shared__ __bf16 Kt[32][72];      // K tile, row-major [keypos][d]
  __shared__ __bf16 Vt[64][40];      // V tile, transposed [d][keypos]
  __shared__ __bf16 Pt[4][16][40];   // per-wave P [qrow][key]

  const int t = threadIdx.x;
  const int w = t >> 6, lane = t & 63;
  const int l15 = lane & 15, g = lane >> 4;
  const int b = blockIdx.z, h = blockIdx.y;
  const int qbase = blockIdx.x * 64 + w * 16;

  // Q fragments: A-layout row=l15, k=g*8+j over d slice [s*32, s*32+32)
  bf16x8 qa[2];
  {
    const float* qptr = qp + ((size_t)(b * SEQ + qbase + l15)) * DIM + h * DHEAD;
    #pragma unroll
    for (int s = 0; s < 2; ++s)
      #pragma unroll
      for (int j = 0; j < 8; ++j)
        qa[s][j] = (__bf16)qptr[s * 32 + g * 8 + j];
  }

  f32x4 O[4];
  #pragma unroll
  for (int f = 0; f < 4; ++f) O[f] = (f32x4){0.f, 0.f, 0.f, 0.f};
  float m[4], lsum[4];
  #pragma unroll
  for (int r = 0; r < 4; ++r) { m[r] = -INFINITY; lsum[r] = 0.f; }

  const __bf16* kb = kbf + (size_t)b * SEQ * DHEAD;
  const __bf16* vb = vbf + (size_t)b * SEQ * DHEAD;

  for (int kt = 0; kt < SEQ / 32; ++kt) {
    const int kp0 = kt * 32;
    {  // cooperative stage: K row-major, V transposed
      int row = t >> 3, d0 = (t & 7) * 8;
      bf16x8 k8 = *(const bf16x8*)&kb[(size_t)(kp0 + row) * DHEAD + d0];
      *(bf16x8*)&Kt[row][d0] = k8;
      bf16x8 v8 = *(const bf16x8*)&vb[(size_t)(kp0 + row) * DHEAD + d0];
      #pragma unroll
      for (int j = 0; j < 8; ++j) Vt[d0 + j][row] = v8[j];
    }
    __syncthreads();

    // S = Q K^T for 2 key sub-tiles of 16
    f32x4 s0 = (f32x4){0.f, 0.f, 0.f, 0.f};
    f32x4 s1 = (f32x4){0.f, 0.f, 0.f, 0.f};
    #pragma unroll
    for (int s = 0; s < 2; ++s) {
      bf16x8 k0f = *(const bf16x8*)&Kt[l15][s * 32 + g * 8];
      bf16x8 k1f = *(const bf16x8*)&Kt[16 + l15][s * 32 + g * 8];
      s0 = mfma16(qa[s], k0f, s0);
      s1 = mfma16(qa[s], k1f, s1);
    }

    // online softmax per row (row = g*4 + r), 16-lane group reductions
    float fac[4];
    #pragma unroll
    for (int r = 0; r < 4; ++r) {
      float a = s0[r] * 0.125f;
      float bq = s1[r] * 0.125f;
      float tm = fmaxf(a, bq);
      #pragma unroll
      for (int off = 1; off < 16; off <<= 1) tm = fmaxf(tm, __shfl_xor(tm, off));
      float mn = fmaxf(m[r], tm);
      fac[r] = __expf(m[r] - mn);
      float p0 = __expf(a - mn);
      float p1 = __expf(bq - mn);
      float rs = p0 + p1;
      #pragma unroll
      for (int off = 1; off < 16; off <<= 1) rs += __shfl_xor(rs, off);
      lsum[r] = lsum[r] * fac[r] + rs;
      m[r] = mn;
      int row = g * 4 + r;
      Pt[w][row][l15]      = (__bf16)p0;
      Pt[w][row][16 + l15] = (__bf16)p1;
    }
    #pragma unroll
    for (int f = 0; f < 4; ++f)
      #pragma unroll
      for (int r = 0; r < 4; ++r) O[f][r] *= fac[r];
    __syncthreads();

    // O += P V  (A = P 16x32, B = V 32x16 per 16-dim group)
    bf16x8 pa = *(const bf16x8*)&Pt[w][l15][g * 8];
    #pragma unroll
    for (int f = 0; f < 4; ++f) {
      bf16x8 vf = *(const bf16x8*)&Vt[f * 16 + l15][g * 8];
      O[f] = mfma16(pa, vf, O[f]);
    }
    __syncthreads();
  }

  #pragma unroll
  for (int r = 0; r < 4; ++r) {
    float inv = 1.f / lsum[r];
    size_t row = (size_t)(b * SEQ + qbase + g * 4 + r);
    #pragma unroll
    for (int f = 0; f < 4; ++f)
      attn_out[row * DIM + h * DHEAD + f * 16 + l15] = O[f][r] * inv;
  }
}

// ---------------------------------------------------------------------------
extern "C" void kernel_launch(void* const* d_in, const int* in_sizes, int n_in,
                              void* d_out, int out_size, void* d_ws, size_t ws_size,
                              hipStream_t stream) {
  const float* q        = (const float*)d_in[0];
  // d_in[1] = kv (unused by the reference forward)
  const float* mem      = (const float*)d_in[2];
  const float* w_q      = (const float*)d_in[3];
  const float* w_kv     = (const float*)d_in[4];
  const float* w_concat = (const float*)d_in[5];
  float* out = (float*)d_out;

  char* wsb = (char*)d_ws;
  float* qp       = (float*)(wsb + 0);                       // 32 MB
  float* attn_out = (float*)(wsb + (size_t)33554432);        // 32 MB
  float* pv       = (float*)(wsb + (size_t)67108864);        // 128 KB
  int*   pi       = (int*)  (wsb + (size_t)67239936);        // 128 KB
  int*   idx      = (int*)  (wsb + (size_t)67371008);        // 32 KB
  __bf16* kbf     = (__bf16*)(wsb + (size_t)67403776);       // 1 MB
  __bf16* vbf     = (__bf16*)(wsb + (size_t)68452352);       // 1 MB

  // 1. qp = q @ w_q   (f32: feeds the argmax-critical kNN path)
  gemm_f32<<<dim3(ROWS / 128, DIM / 64), 256, 0, stream>>>(q, w_q, qp, ROWS, DIM, DIM);
  // 2. kNN argmax over 1000 memories
  knn_partial<<<dim3(ROWS / 64, 4), 256, 0, stream>>>(qp, mem, pv, pi);
  knn_reduce<<<dim3(ROWS / 256), 256, 0, stream>>>(pv, pi, idx);
  // 3. gather + @ w_kv -> k, v (bf16)
  kv_gemm<<<dim3(ROWS / 64), 256, 0, stream>>>(mem, idx, w_kv, kbf, vbf);
  // 4. flash attention (bf16 MFMA)
  flash_attn<<<dim3(SEQ / 64, NHEAD, BATCH), 256, 0, stream>>>(qp, kbf, vbf, attn_out);
  // 5. out = attn_out @ w_concat
  gemm_f32<<<dim3(ROWS / 128, DIM / 64), 256, 0, stream>>>(attn_out, w_concat, out, ROWS, DIM, DIM);
}

// Round 2
// 639.688 us; speedup vs baseline: 3.2881x; 3.2881x over previous
//
#include <hip/hip_runtime.h>
#include <float.h>
#include <math.h>

// KNNAttention: b=4, l=2048, d=1024, h=16, dh=64, n_mem=1000
#define BATCH 4
#define SEQ   2048
#define DIM   1024
#define NHEAD 16
#define DHEAD 64
#define NMEM  1000
#define ROWS  (BATCH*SEQ)   // 8192

typedef __attribute__((ext_vector_type(8))) __bf16 bf16x8;
typedef __attribute__((ext_vector_type(4))) float  f32x4;

static __device__ inline f32x4 mfma16(bf16x8 a, bf16x8 b, f32x4 c) {
  return __builtin_amdgcn_mfma_f32_16x16x32_bf16(a, b, c, 0, 0, 0);
}

// async global->LDS, 16B per lane. LDS dest must be wave-uniform base (+lane*16).
#define GLOAD16(g, l) __builtin_amdgcn_global_load_lds( \
    (const __attribute__((address_space(1))) unsigned int*)(g), \
    (__attribute__((address_space(3))) unsigned int*)(l), 16, 0, 0)

enum { MODE_C = 0, MODE_HILO = 1, MODE_ARGMAX = 2 };

// ---------------------------------------------------------------------------
// Fused split-bf16 GEMM: C = sum of up to 3 products (Ah*Bh + Ah*Bl + Al*Bh),
// C = A * B^T, A: [M][1024], Bt: [N=1024][1024] (both row-major, K inner).
// Tile 128x128, BK=32, 4 waves (2x2 of 64x64). m97-style staging via
// global_load_lds with XOR-swizzled global source + swizzled LDS reads.
// AF32=1: A is f32, split to hi/lo in-register (used for qp = q @ w_q).
// ---------------------------------------------------------------------------
template<int AF32, int NPROD, int MODE>
__global__ __launch_bounds__(256) void gemm3(
    const void* __restrict__ Ah_, const __bf16* __restrict__ Al,
    const __bf16* __restrict__ Bh, const __bf16* __restrict__ Bl,
    int rowsPerZ, long bStrideZ,
    float* __restrict__ C, __bf16* __restrict__ Oh, __bf16* __restrict__ Ol,
    float* __restrict__ pv, int* __restrict__ pi)
{
  extern __shared__ char smem[];
  __shared__ float s_pv[128];
  __shared__ int   s_pi[128];
  const int t = threadIdx.x;
  const int w = t >> 6, lane = t & 63, l15 = lane & 15, g = lane >> 4;
  const int wr = w >> 1, wc = w & 1;
  const int m0 = blockIdx.z * rowsPerZ + blockIdx.x * 128;
  const int n0 = blockIdx.y * 128;
  const __bf16* Bh_b = Bh + (size_t)blockIdx.z * bStrideZ;
  const __bf16* Bl_b = (NPROD == 3) ? (Bl + (size_t)blockIdx.z * bStrideZ) : (const __bf16*)0;

  char* sA  = smem;                                            // f32 16KB or bf16 8KB
  char* sAl = smem + 8192;                                     // bf16 lo (AF32==0,NPROD==3)
  char* sBh = smem + (AF32 ? 16384 : (NPROD == 3 ? 16384 : 8192));
  char* sBl = sBh + 8192;

  f32x4 acc[4][4];
  #pragma unroll
  for (int i = 0; i < 4; ++i)
    #pragma unroll
    for (int j = 0; j < 4; ++j) acc[i][j] = (f32x4){0.f, 0.f, 0.f, 0.f};

  for (int k0 = 0; k0 < DIM; k0 += 32) {
    // ---- stage A ----
    if (AF32) {
      const float* Af = (const float*)Ah_;
      #pragma unroll
      for (int i = 0; i < 4; ++i) {
        int c = i * 256 + t;
        int r = c >> 3, s = c & 7;
        int sl = s ^ (r & 7);                 // pre-swizzled source slot (16B units)
        GLOAD16(&Af[(size_t)(m0 + r) * DIM + k0 + sl * 4], sA + i * 4096 + w * 1024);
      }
    } else {
      const __bf16* Ab = (const __bf16*)Ah_;
      #pragma unroll
      for (int i = 0; i < 2; ++i) {
        int c = i * 256 + t;
        int r = c >> 2, s = c & 3;
        int sl = s ^ (r & 3);
        GLOAD16(&Ab[(size_t)(m0 + r) * DIM + k0 + sl * 8], sA + i * 4096 + w * 1024);
        if (NPROD == 3)
          GLOAD16(&Al[(size_t)(m0 + r) * DIM + k0 + sl * 8], sAl + i * 4096 + w * 1024);
      }
    }
    // ---- stage B ----
    #pragma unroll
    for (int i = 0; i < 2; ++i) {
      int c = i * 256 + t;
      int r = c >> 2, s = c & 3;
      int sl = s ^ (r & 3);
      GLOAD16(&Bh_b[(size_t)(n0 + r) * DIM + k0 + sl * 8], sBh + i * 4096 + w * 1024);
      if (NPROD == 3)
        GLOAD16(&Bl_b[(size_t)(n0 + r) * DIM + k0 + sl * 8], sBl + i * 4096 + w * 1024);
    }
    __syncthreads();

    // ---- fragments (swizzled LDS reads) ----
    bf16x8 ah[4], al[4], bh[4], bl[4];
    #pragma unroll
    for (int mi = 0; mi < 4; ++mi) {
      int r = wr * 64 + mi * 16 + l15;
      if (AF32) {
        int p0 = (2 * g) ^ (r & 7), p1 = (2 * g + 1) ^ (r & 7);
        float4 q0 = *(const float4*)(sA + r * 128 + p0 * 16);
        float4 q1 = *(const float4*)(sA + r * 128 + p1 * 16);
        float qq[8] = {q0.x, q0.y, q0.z, q0.w, q1.x, q1.y, q1.z, q1.w};
        #pragma unroll
        for (int j = 0; j < 8; ++j) {
          __bf16 h = (__bf16)qq[j];
          ah[mi][j] = h;
          al[mi][j] = (__bf16)(qq[j] - (float)h);
        }
      } else {
        int p = (g ^ (r & 3)) * 16;
        ah[mi] = *(const bf16x8*)(sA + r * 64 + p);
        if (NPROD == 3) al[mi] = *(const bf16x8*)(sAl + r * 64 + p);
      }
    }
    #pragma unroll
    for (int ni = 0; ni < 4; ++ni) {
      int r = wc * 64 + ni * 16 + l15;
      int p = (g ^ (r & 3)) * 16;
      bh[ni] = *(const bf16x8*)(sBh + r * 64 + p);
      if (NPROD == 3) bl[ni] = *(const bf16x8*)(sBl + r * 64 + p);
    }
    #pragma unroll
    for (int mi = 0; mi < 4; ++mi)
      #pragma unroll
      for (int ni = 0; ni < 4; ++ni) {
        acc[mi][ni] = mfma16(ah[mi], bh[ni], acc[mi][ni]);
        if (NPROD == 3) {
          acc[mi][ni] = mfma16(ah[mi], bl[ni], acc[mi][ni]);
          acc[mi][ni] = mfma16(al[mi], bh[ni], acc[mi][ni]);
        }
      }
    __syncthreads();
  }

  // ---- epilogue ----
  if (MODE == MODE_C) {
    #pragma unroll
    for (int mi = 0; mi < 4; ++mi)
      #pragma unroll
      for (int ni = 0; ni < 4; ++ni) {
        int col = n0 + wc * 64 + ni * 16 + l15;
        #pragma unroll
        for (int r = 0; r < 4; ++r) {
          int row = m0 + wr * 64 + mi * 16 + g * 4 + r;
          C[(size_t)row * DIM + col] = acc[mi][ni][r];
        }
      }
  } else if (MODE == MODE_HILO) {
    #pragma unroll
    for (int mi = 0; mi < 4; ++mi)
      #pragma unroll
      for (int ni = 0; ni < 4; ++ni) {
        int col = n0 + wc * 64 + ni * 16 + l15;
        #pragma unroll
        for (int r = 0; r < 4; ++r) {
          int row = m0 + wr * 64 + mi * 16 + g * 4 + r;
          float v = acc[mi][ni][r];
          __bf16 h = (__bf16)v;
          Oh[(size_t)row * DIM + col] = h;
          Ol[(size_t)row * DIM + col] = (__bf16)(v - (float)h);
        }
      }
  } else {  // MODE_ARGMAX: per-row argmax over this block's 128 cols
    float vv[4][4]; int ii[4][4];
    #pragma unroll
    for (int mi = 0; mi < 4; ++mi)
      #pragma unroll
      for (int r = 0; r < 4; ++r) {
        float v = -FLT_MAX; int vi = 0x7fffffff;
        #pragma unroll
        for (int ni = 0; ni < 4; ++ni) {
          int col = n0 + wc * 64 + ni * 16 + l15;
          float s = (col < NMEM) ? acc[mi][ni][r] : -FLT_MAX;
          if (s > v) { v = s; vi = col; }
        }
        #pragma unroll
        for (int off = 1; off < 16; off <<= 1) {
          float ov = __shfl_xor(v, off);
          int   oi = __shfl_xor(vi, off);
          if (ov > v || (ov == v && oi < vi)) { v = ov; vi = oi; }
        }
        vv[mi][r] = v; ii[mi][r] = vi;
        if (wc == 0 && l15 == 0) {
          int lrow = wr * 64 + mi * 16 + g * 4 + r;
          s_pv[lrow] = v; s_pi[lrow] = vi;
        }
      }
    __syncthreads();
    if (wc == 1 && l15 == 0) {
      #pragma unroll
      for (int mi = 0; mi < 4; ++mi)
        #pragma unroll
        for (int r = 0; r < 4; ++r) {
          int lrow = wr * 64 + mi * 16 + g * 4 + r;
          float v0 = s_pv[lrow]; int i0 = s_pi[lrow];
          float v1 = vv[mi][r];  int i1 = ii[mi][r];
          float v; int vi;
          if (v1 > v0) { v = v1; vi = i1; } else { v = v0; vi = i0; }  // tie -> lower col (wc0)
          pv[(size_t)blockIdx.y * ROWS + m0 + lrow] = v;
          pi[(size_t)blockIdx.y * ROWS + m0 + lrow] = vi;
        }
    }
  }
}

// ---------------------------------------------------------------------------
// Combine the 8 column-tile argmax partials (ascending col tiles -> first-max).
// ---------------------------------------------------------------------------
__global__ __launch_bounds__(256) void knn_reduce(const float* __restrict__ pv,
                                                  const int* __restrict__ pi,
                                                  int* __restrict__ idx) {
  int r = blockIdx.x * 256 + threadIdx.x;
  float bv = -FLT_MAX; int bi = 0x7fffffff;
  #pragma unroll
  for (int c = 0; c < 8; ++c) {
    float v = pv[(size_t)c * ROWS + r];
    int   i = pi[(size_t)c * ROWS + r];
    if (v > bv || (v == bv && i < bi)) { bv = v; bi = i; }
  }
  idx[r] = bi;
}

// ---------------------------------------------------------------------------
// Transpose + split-cast weights: in [k][n] f32 -> out [n][k] bf16 hi (+lo).
// ---------------------------------------------------------------------------
__global__ __launch_bounds__(256) void cast_w_t(const float* __restrict__ in,
                                                __bf16* __restrict__ oh,
                                                __bf16* __restrict__ ol,
                                                int writeLo) {
  __shared__ float tile[64][65];
  const int t = threadIdx.x;
  const int k0 = blockIdx.x * 64, n0 = blockIdx.y * 64;
  #pragma unroll
  for (int i = 0; i < 16; ++i) {
    int e = t + i * 256, r = e >> 6, c = e & 63;
    tile[r][c] = in[(size_t)(k0 + r) * DIM + n0 + c];
  }
  __syncthreads();
  #pragma unroll
  for (int i = 0; i < 16; ++i) {
    int e = t + i * 256, r = e >> 6, c = e & 63;   // r: n-dir, c: k-dir
    float v = tile[c][r];
    __bf16 h = (__bf16)v;
    oh[(size_t)(n0 + r) * DIM + k0 + c] = h;
    if (writeLo) ol[(size_t)(n0 + r) * DIM + k0 + c] = (__bf16)(v - (float)h);
  }
}

// mem_table (4,1000,1024) f32 -> hi/lo bf16 padded to (4,1024,1024), pad rows = 0
__global__ __launch_bounds__(256) void cast_mem(const float* __restrict__ mem,
                                                __bf16* __restrict__ mh,
                                                __bf16* __restrict__ ml) {
  size_t e = ((size_t)blockIdx.x * 256 + threadIdx.x) * 8;
  int d = (int)(e & 1023);
  size_t rn = e >> 10;
  int n = (int)(rn & 1023), b = (int)(rn >> 10);
  bf16x8 h8, l8;
  if (n < NMEM) {
    const float* p = mem + ((size_t)b * NMEM + n) * DIM + d;
    #pragma unroll
    for (int j = 0; j < 8; ++j) {
      float v = p[j];
      __bf16 h = (__bf16)v;
      h8[j] = h; l8[j] = (__bf16)(v - (float)h);
    }
  } else {
    #pragma unroll
    for (int j = 0; j < 8; ++j) { h8[j] = (__bf16)0.f; l8[j] = (__bf16)0.f; }
  }
  *(bf16x8*)(mh + e) = h8;
  *(bf16x8*)(ml + e) = l8;
}

// ---------------------------------------------------------------------------
// Gather mem[idx] @ w_kv -> k,v bf16 (unchanged from round 1, works).
// ---------------------------------------------------------------------------
__global__ __launch_bounds__(256) void kv_gemm(const float* __restrict__ mem,
                                               const int* __restrict__ idx,
                                               const float* __restrict__ w_kv,
                                               __bf16* __restrict__ kbf,
                                               __bf16* __restrict__ vbf) {
  __shared__ float As[16][68];
  __shared__ float Bs[16][128];
  __shared__ int sidx[64];
  const int t = threadIdx.x;
  const int m0 = blockIdx.x * 64;
  const int batch = m0 >> 11;
  if (t < 64) sidx[t] = idx[m0 + t];
  __syncthreads();
  const int tx = t & 31, ty = t >> 5;
  float acc[8][4] = {};
  for (int k0 = 0; k0 < DIM; k0 += 16) {
    #pragma unroll
    for (int i = 0; i < 4; ++i) {
      int e = t + 256 * i, r = e >> 4, c = e & 15;
      As[c][r] = mem[((size_t)batch * NMEM + sidx[r]) * DIM + k0 + c];
    }
    #pragma unroll
    for (int i = 0; i < 8; ++i) {
      int e = t + 256 * i, r = e >> 7, c = e & 127;
      Bs[r][c] = w_kv[(size_t)(k0 + r) * 128 + c];
    }
    __syncthreads();
    #pragma unroll
    for (int k = 0; k < 16; ++k) {
      float4 a0 = *(const float4*)&As[k][ty * 8];
      float4 a1 = *(const float4*)&As[k][ty * 8 + 4];
      float4 bv = *(const float4*)&Bs[k][tx * 4];
      float av[8] = {a0.x, a0.y, a0.z, a0.w, a1.x, a1.y, a1.z, a1.w};
      float bb[4] = {bv.x, bv.y, bv.z, bv.w};
      #pragma unroll
      for (int i = 0; i < 8; ++i)
        #pragma unroll
        for (int j = 0; j < 4; ++j)
          acc[i][j] = fmaf(av[i], bb[j], acc[i][j]);
    }
    __syncthreads();
  }
  #pragma unroll
  for (int i = 0; i < 8; ++i) {
    int row = m0 + ty * 8 + i;
    #pragma unroll
    for (int j = 0; j < 4; ++j) {
      int col = tx * 4 + j;
      __bf16 hv = (__bf16)acc[i][j];
      if (col < DHEAD) kbf[(size_t)row * DHEAD + col] = hv;
      else             vbf[(size_t)row * DHEAD + (col - DHEAD)] = hv;
    }
  }
}

// ---------------------------------------------------------------------------
// Flash attention (round-1 verified), Q from bf16 qph, out to bf16.
// ---------------------------------------------------------------------------
__global__ __launch_bounds__(256) void flash_attn(const __bf16* __restrict__ qph,
                                                  const __bf16* __restrict__ kbf,
                                                  const __bf16* __restrict__ vbf,
                                                  __bf16* __restrict__ attn_bf) {
  __shared__ __bf16 Kt[32][72];
  __shared__ __bf16 Vt[64][40];
  __shared__ __bf16 Pt[4][16][40];

  const int t = threadIdx.x;
  const int w = t >> 6, lane = t & 63;
  const int l15 = lane & 15, g = lane >> 4;
  const int b = blockIdx.z, h = blockIdx.y;
  const int qbase = blockIdx.x * 64 + w * 16;

  bf16x8 qa[2];
  {
    const __bf16* qptr = qph + ((size_t)(b * SEQ + qbase + l15)) * DIM + h * DHEAD;
    qa[0] = *(const bf16x8*)(qptr + g * 8);
    qa[1] = *(const bf16x8*)(qptr + 32 + g * 8);
  }

  f32x4 O[4];
  #pragma unroll
  for (int f = 0; f < 4; ++f) O[f] = (f32x4){0.f, 0.f, 0.f, 0.f};
  float m[4], lsum[4];
  #pragma unroll
  for (int r = 0; r < 4; ++r) { m[r] = -INFINITY; lsum[r] = 0.f; }

  const __bf16* kb = kbf + (size_t)b * SEQ * DHEAD;
  const __bf16* vb = vbf + (size_t)b * SEQ * DHEAD;

  for (int kt = 0; kt < SEQ / 32; ++kt) {
    const int kp0 = kt * 32;
    {
      int row = t >> 3, d0 = (t & 7) * 8;
      bf16x8 k8 = *(const bf16x8*)&kb[(size_t)(kp0 + row) * DHEAD + d0];
      *(bf16x8*)&Kt[row][d0] = k8;
      bf16x8 v8 = *(const bf16x8*)&vb[(size_t)(kp0 + row) * DHEAD + d0];
      #pragma unroll
      for (int j = 0; j < 8; ++j) Vt[d0 + j][row] = v8[j];
    }
    __syncthreads();

    f32x4 s0 = (f32x4){0.f, 0.f, 0.f, 0.f};
    f32x4 s1 = (f32x4){0.f, 0.f, 0.f, 0.f};
    #pragma unroll
    for (int s = 0; s < 2; ++s) {
      bf16x8 k0f = *(const bf16x8*)&Kt[l15][s * 32 + g * 8];
      bf16x8 k1f = *(const bf16x8*)&Kt[16 + l15][s * 32 + g * 8];
      s0 = mfma16(qa[s], k0f, s0);
      s1 = mfma16(qa[s], k1f, s1);
    }

    float fac[4];
    #pragma unroll
    for (int r = 0; r < 4; ++r) {
      float a = s0[r] * 0.125f;
      float bq = s1[r] * 0.125f;
      float tm = fmaxf(a, bq);
      #pragma unroll
      for (int off = 1; off < 16; off <<= 1) tm = fmaxf(tm, __shfl_xor(tm, off));
      float mn = fmaxf(m[r], tm);
      fac[r] = __expf(m[r] - mn);
      float p0 = __expf(a - mn);
      float p1 = __expf(bq - mn);
      float rs = p0 + p1;
      #pragma unroll
      for (int off = 1; off < 16; off <<= 1) rs += __shfl_xor(rs, off);
      lsum[r] = lsum[r] * fac[r] + rs;
      m[r] = mn;
      int row = g * 4 + r;
      Pt[w][row][l15]      = (__bf16)p0;
      Pt[w][row][16 + l15] = (__bf16)p1;
    }
    #pragma unroll
    for (int f = 0; f < 4; ++f)
      #pragma unroll
      for (int r = 0; r < 4; ++r) O[f][r] *= fac[r];
    __syncthreads();

    bf16x8 pa = *(const bf16x8*)&Pt[w][l15][g * 8];
    #pragma unroll
    for (int f = 0; f < 4; ++f) {
      bf16x8 vf = *(const bf16x8*)&Vt[f * 16 + l15][g * 8];
      O[f] = mfma16(pa, vf, O[f]);
    }
    __syncthreads();
  }

  #pragma unroll
  for (int r = 0; r < 4; ++r) {
    float inv = 1.f / lsum[r];
    size_t row = (size_t)(b * SEQ + qbase + g * 4 + r);
    #pragma unroll
    for (int f = 0; f < 4; ++f)
      attn_bf[row * DIM + h * DHEAD + f * 16 + l15] = (__bf16)(O[f][r] * inv);
  }
}

// ---------------------------------------------------------------------------
extern "C" void kernel_launch(void* const* d_in, const int* in_sizes, int n_in,
                              void* d_out, int out_size, void* d_ws, size_t ws_size,
                              hipStream_t stream) {
  const float* q        = (const float*)d_in[0];
  const float* mem      = (const float*)d_in[2];
  const float* w_q      = (const float*)d_in[3];
  const float* w_kv     = (const float*)d_in[4];
  const float* w_concat = (const float*)d_in[5];
  float* out = (float*)d_out;

  char* wsb = (char*)d_ws;
  __bf16* memh  = (__bf16*)(wsb + 0);                  //  8 MiB (4x1024x1024)
  __bf16* meml  = (__bf16*)(wsb + 8388608);            //  8 MiB
  __bf16* wqt_h = (__bf16*)(wsb + 16777216);           //  2 MiB
  __bf16* wqt_l = (__bf16*)(wsb + 18874368);           //  2 MiB
  __bf16* wct   = (__bf16*)(wsb + 20971520);           //  2 MiB
  __bf16* kbf   = (__bf16*)(wsb + 23068672);           //  1 MiB
  __bf16* vbf   = (__bf16*)(wsb + 24117248);           //  1 MiB
  float*  pv    = (float*) (wsb + 25165824);           //  256 KiB
  int*    pi    = (int*)   (wsb + 25427968);           //  256 KiB
  int*    idx   = (int*)   (wsb + 25690112);           //  32 KiB
  __bf16* qph   = (__bf16*)(wsb + 25722880);           // 16 MiB
  __bf16* qpl   = (__bf16*)(wsb + 42500096);           // 16 MiB (reused as attn_bf)
  __bf16* attn_bf = qpl;                               // qpl dead after scores

  // weight casts
  cast_w_t<<<dim3(16, 16), 256, 0, stream>>>(w_q, wqt_h, wqt_l, 1);
  cast_w_t<<<dim3(16, 16), 256, 0, stream>>>(w_concat, wct, (__bf16*)0, 0);
  cast_mem<<<dim3(2048), 256, 0, stream>>>(mem, memh, meml);

  // qp = q @ w_q (A f32 in-kernel split, 3 products) -> qph/qpl bf16
  gemm3<1, 3, MODE_HILO><<<dim3(64, 8, 1), 256, 32768, stream>>>(
      (const void*)q, (const __bf16*)0, wqt_h, wqt_l, 0, 0,
      (float*)0, qph, qpl, (float*)0, (int*)0);

  // scores = qp @ mem^T per batch, fused argmax partials
  gemm3<0, 3, MODE_ARGMAX><<<dim3(16, 8, 4), 256, 32768, stream>>>(
      (const void*)qph, qpl, memh, meml, 2048, (long)1024 * 1024,
      (float*)0, (__bf16*)0, (__bf16*)0, pv, pi);
  knn_reduce<<<dim3(32), 256, 0, stream>>>(pv, pi, idx);

  // k,v = gather(mem, idx) @ w_kv
  kv_gemm<<<dim3(ROWS / 64), 256, 0, stream>>>(mem, idx, w_kv, kbf, vbf);

  // flash attention
  flash_attn<<<dim3(SEQ / 64, NHEAD, BATCH), 256, 0, stream>>>(qph, kbf, vbf, attn_bf);

  // out = attn @ w_concat (single-product bf16)
  gemm3<0, 1, MODE_C><<<dim3(64, 8, 1), 256, 16384, stream>>>(
      (const void*)attn_bf, (const __bf16*)0, wct, (const __bf16*)0, 0, 0,
      out, (__bf16*)0, (__bf16*)0, (float*)0, (int*)0);
}

// Round 3
// 411.605 us; speedup vs baseline: 5.1101x; 1.5541x over previous
//
#include <hip/hip_runtime.h>
#include <float.h>
#include <math.h>

// KNNAttention: b=4, l=2048, d=1024, h=16, dh=64, n_mem=1000
#define BATCH 4
#define SEQ   2048
#define DIM   1024
#define NHEAD 16
#define DHEAD 64
#define NMEM  1000
#define NPAD  1024          // padded memory slots
#define ROWS  (BATCH*SEQ)   // 8192

typedef __attribute__((ext_vector_type(8))) __bf16 bf16x8;
typedef __attribute__((ext_vector_type(4))) float  f32x4;

static __device__ inline f32x4 mfma16(bf16x8 a, bf16x8 b, f32x4 c) {
  return __builtin_amdgcn_mfma_f32_16x16x32_bf16(a, b, c, 0, 0, 0);
}

// async global->LDS, 16B per lane. LDS dest must be wave-uniform base (+lane*16).
#define GLOAD16(g, l) __builtin_amdgcn_global_load_lds( \
    (const __attribute__((address_space(1))) unsigned int*)(g), \
    (__attribute__((address_space(3))) unsigned int*)(l), 16, 0, 0)

enum { MODE_C = 0, MODE_HILO = 1, MODE_ARGMAX = 2 };

// ---------------------------------------------------------------------------
// Fused split-bf16 GEMM (verified round 2): C = A * B^T, up to 3 products.
// ---------------------------------------------------------------------------
template<int AF32, int NPROD, int MODE>
__global__ __launch_bounds__(256) void gemm3(
    const void* __restrict__ Ah_, const __bf16* __restrict__ Al,
    const __bf16* __restrict__ Bh, const __bf16* __restrict__ Bl,
    int rowsPerZ, long bStrideZ,
    float* __restrict__ C, __bf16* __restrict__ Oh, __bf16* __restrict__ Ol,
    float* __restrict__ pv, int* __restrict__ pi)
{
  extern __shared__ char smem[];
  __shared__ float s_pv[128];
  __shared__ int   s_pi[128];
  const int t = threadIdx.x;
  const int w = t >> 6, lane = t & 63, l15 = lane & 15, g = lane >> 4;
  const int wr = w >> 1, wc = w & 1;
  const int m0 = blockIdx.z * rowsPerZ + blockIdx.x * 128;
  const int n0 = blockIdx.y * 128;
  const __bf16* Bh_b = Bh + (size_t)blockIdx.z * bStrideZ;
  const __bf16* Bl_b = (NPROD == 3) ? (Bl + (size_t)blockIdx.z * bStrideZ) : (const __bf16*)0;

  char* sA  = smem;
  char* sAl = smem + 8192;
  char* sBh = smem + (AF32 ? 16384 : (NPROD == 3 ? 16384 : 8192));
  char* sBl = sBh + 8192;

  f32x4 acc[4][4];
  #pragma unroll
  for (int i = 0; i < 4; ++i)
    #pragma unroll
    for (int j = 0; j < 4; ++j) acc[i][j] = (f32x4){0.f, 0.f, 0.f, 0.f};

  for (int k0 = 0; k0 < DIM; k0 += 32) {
    if (AF32) {
      const float* Af = (const float*)Ah_;
      #pragma unroll
      for (int i = 0; i < 4; ++i) {
        int c = i * 256 + t;
        int r = c >> 3, s = c & 7;
        int sl = s ^ (r & 7);
        GLOAD16(&Af[(size_t)(m0 + r) * DIM + k0 + sl * 4], sA + i * 4096 + w * 1024);
      }
    } else {
      const __bf16* Ab = (const __bf16*)Ah_;
      #pragma unroll
      for (int i = 0; i < 2; ++i) {
        int c = i * 256 + t;
        int r = c >> 2, s = c & 3;
        int sl = s ^ (r & 3);
        GLOAD16(&Ab[(size_t)(m0 + r) * DIM + k0 + sl * 8], sA + i * 4096 + w * 1024);
        if (NPROD == 3)
          GLOAD16(&Al[(size_t)(m0 + r) * DIM + k0 + sl * 8], sAl + i * 4096 + w * 1024);
      }
    }
    #pragma unroll
    for (int i = 0; i < 2; ++i) {
      int c = i * 256 + t;
      int r = c >> 2, s = c & 3;
      int sl = s ^ (r & 3);
      GLOAD16(&Bh_b[(size_t)(n0 + r) * DIM + k0 + sl * 8], sBh + i * 4096 + w * 1024);
      if (NPROD == 3)
        GLOAD16(&Bl_b[(size_t)(n0 + r) * DIM + k0 + sl * 8], sBl + i * 4096 + w * 1024);
    }
    __syncthreads();

    bf16x8 ah[4], al[4], bh[4], bl[4];
    #pragma unroll
    for (int mi = 0; mi < 4; ++mi) {
      int r = wr * 64 + mi * 16 + l15;
      if (AF32) {
        int p0 = (2 * g) ^ (r & 7), p1 = (2 * g + 1) ^ (r & 7);
        float4 q0 = *(const float4*)(sA + r * 128 + p0 * 16);
        float4 q1 = *(const float4*)(sA + r * 128 + p1 * 16);
        float qq[8] = {q0.x, q0.y, q0.z, q0.w, q1.x, q1.y, q1.z, q1.w};
        #pragma unroll
        for (int j = 0; j < 8; ++j) {
          __bf16 h = (__bf16)qq[j];
          ah[mi][j] = h;
          al[mi][j] = (__bf16)(qq[j] - (float)h);
        }
      } else {
        int p = (g ^ (r & 3)) * 16;
        ah[mi] = *(const bf16x8*)(sA + r * 64 + p);
        if (NPROD == 3) al[mi] = *(const bf16x8*)(sAl + r * 64 + p);
      }
    }
    #pragma unroll
    for (int ni = 0; ni < 4; ++ni) {
      int r = wc * 64 + ni * 16 + l15;
      int p = (g ^ (r & 3)) * 16;
      bh[ni] = *(const bf16x8*)(sBh + r * 64 + p);
      if (NPROD == 3) bl[ni] = *(const bf16x8*)(sBl + r * 64 + p);
    }
    #pragma unroll
    for (int mi = 0; mi < 4; ++mi)
      #pragma unroll
      for (int ni = 0; ni < 4; ++ni) {
        acc[mi][ni] = mfma16(ah[mi], bh[ni], acc[mi][ni]);
        if (NPROD == 3) {
          acc[mi][ni] = mfma16(ah[mi], bl[ni], acc[mi][ni]);
          acc[mi][ni] = mfma16(al[mi], bh[ni], acc[mi][ni]);
        }
      }
    __syncthreads();
  }

  if (MODE == MODE_C) {
    #pragma unroll
    for (int mi = 0; mi < 4; ++mi)
      #pragma unroll
      for (int ni = 0; ni < 4; ++ni) {
        int col = n0 + wc * 64 + ni * 16 + l15;
        #pragma unroll
        for (int r = 0; r < 4; ++r) {
          int row = m0 + wr * 64 + mi * 16 + g * 4 + r;
          C[(size_t)row * DIM + col] = acc[mi][ni][r];
        }
      }
  } else if (MODE == MODE_HILO) {
    #pragma unroll
    for (int mi = 0; mi < 4; ++mi)
      #pragma unroll
      for (int ni = 0; ni < 4; ++ni) {
        int col = n0 + wc * 64 + ni * 16 + l15;
        #pragma unroll
        for (int r = 0; r < 4; ++r) {
          int row = m0 + wr * 64 + mi * 16 + g * 4 + r;
          float v = acc[mi][ni][r];
          __bf16 h = (__bf16)v;
          Oh[(size_t)row * DIM + col] = h;
          Ol[(size_t)row * DIM + col] = (__bf16)(v - (float)h);
        }
      }
  } else {
    float vv[4][4]; int ii[4][4];
    #pragma unroll
    for (int mi = 0; mi < 4; ++mi)
      #pragma unroll
      for (int r = 0; r < 4; ++r) {
        float v = -FLT_MAX; int vi = 0x7fffffff;
        #pragma unroll
        for (int ni = 0; ni < 4; ++ni) {
          int col = n0 + wc * 64 + ni * 16 + l15;
          float s = (col < NMEM) ? acc[mi][ni][r] : -FLT_MAX;
          if (s > v) { v = s; vi = col; }
        }
        #pragma unroll
        for (int off = 1; off < 16; off <<= 1) {
          float ov = __shfl_xor(v, off);
          int   oi = __shfl_xor(vi, off);
          if (ov > v || (ov == v && oi < vi)) { v = ov; vi = oi; }
        }
        vv[mi][r] = v; ii[mi][r] = vi;
        if (wc == 0 && l15 == 0) {
          int lrow = wr * 64 + mi * 16 + g * 4 + r;
          s_pv[lrow] = v; s_pi[lrow] = vi;
        }
      }
    __syncthreads();
    if (wc == 1 && l15 == 0) {
      #pragma unroll
      for (int mi = 0; mi < 4; ++mi)
        #pragma unroll
        for (int r = 0; r < 4; ++r) {
          int lrow = wr * 64 + mi * 16 + g * 4 + r;
          float v0 = s_pv[lrow]; int i0 = s_pi[lrow];
          float v1 = vv[mi][r];  int i1 = ii[mi][r];
          float v; int vi;
          if (v1 > v0) { v = v1; vi = i1; } else { v = v0; vi = i0; }
          pv[(size_t)blockIdx.y * ROWS + m0 + lrow] = v;
          pi[(size_t)blockIdx.y * ROWS + m0 + lrow] = vi;
        }
    }
  }
}

__global__ __launch_bounds__(256) void knn_reduce(const float* __restrict__ pv,
                                                  const int* __restrict__ pi,
                                                  int* __restrict__ idx) {
  int r = blockIdx.x * 256 + threadIdx.x;
  float bv = -FLT_MAX; int bi = 0x7fffffff;
  #pragma unroll
  for (int c = 0; c < 8; ++c) {
    float v = pv[(size_t)c * ROWS + r];
    int   i = pi[(size_t)c * ROWS + r];
    if (v > bv || (v == bv && i < bi)) { bv = v; bi = i; }
  }
  idx[r] = bi;
}

// ---------------------------------------------------------------------------
// Per-batch histogram of idx -> log-count bias (masked slots = -1e30).
// ---------------------------------------------------------------------------
__global__ __launch_bounds__(256) void hist_lc(const int* __restrict__ idx,
                                               float* __restrict__ lc) {
  __shared__ int hcnt[NPAD];
  const int t = threadIdx.x, b = blockIdx.x;
  #pragma unroll
  for (int i = 0; i < 4; ++i) hcnt[t + 256 * i] = 0;
  __syncthreads();
  #pragma unroll
  for (int i = 0; i < 8; ++i) atomicAdd(&hcnt[idx[b * SEQ + i * 256 + t]], 1);
  __syncthreads();
  #pragma unroll
  for (int i = 0; i < 4; ++i) {
    int n = t + 256 * i;
    int c = hcnt[n];
    lc[b * NPAD + n] = (n < NMEM && c > 0) ? logf((float)c) : -1e30f;
  }
}

// ---------------------------------------------------------------------------
// K/V table build: all mem rows @ w_kv. Ktab [b][1024][64] bf16 (pad rows 0),
// VtT [b][64][1024] bf16 transposed (pad cols 0).
// ---------------------------------------------------------------------------
__global__ __launch_bounds__(256) void table_gemm(const float* __restrict__ mem,
                                                  const float* __restrict__ w_kv,
                                                  __bf16* __restrict__ Ktab,
                                                  __bf16* __restrict__ VtT) {
  __shared__ float As[16][68];
  __shared__ float Bs[16][128];
  const int t = threadIdx.x;
  const int m0 = blockIdx.x * 64;
  const int tx = t & 31, ty = t >> 5;
  float acc[8][4] = {};
  for (int k0 = 0; k0 < DIM; k0 += 16) {
    #pragma unroll
    for (int i = 0; i < 4; ++i) {
      int e = t + 256 * i, r = e >> 4, c = e & 15;
      int gr = m0 + r, bb = gr >> 10, n = gr & 1023;
      As[c][r] = (n < NMEM) ? mem[((size_t)bb * NMEM + n) * DIM + k0 + c] : 0.f;
    }
    #pragma unroll
    for (int i = 0; i < 8; ++i) {
      int e = t + 256 * i, r = e >> 7, c = e & 127;
      Bs[r][c] = w_kv[(size_t)(k0 + r) * 128 + c];
    }
    __syncthreads();
    #pragma unroll
    for (int k = 0; k < 16; ++k) {
      float4 a0 = *(const float4*)&As[k][ty * 8];
      float4 a1 = *(const float4*)&As[k][ty * 8 + 4];
      float4 bv = *(const float4*)&Bs[k][tx * 4];
      float av[8] = {a0.x, a0.y, a0.z, a0.w, a1.x, a1.y, a1.z, a1.w};
      float bb[4] = {bv.x, bv.y, bv.z, bv.w};
      #pragma unroll
      for (int i = 0; i < 8; ++i)
        #pragma unroll
        for (int j = 0; j < 4; ++j)
          acc[i][j] = fmaf(av[i], bb[j], acc[i][j]);
    }
    __syncthreads();
  }
  #pragma unroll
  for (int i = 0; i < 8; ++i) {
    int gr = m0 + ty * 8 + i, bb = gr >> 10, n = gr & 1023;
    #pragma unroll
    for (int j = 0; j < 4; ++j) {
      int col = tx * 4 + j;
      __bf16 hv = (__bf16)acc[i][j];
      if (col < DHEAD) Ktab[(size_t)gr * DHEAD + col] = hv;
      else             VtT[((size_t)bb * DHEAD + (col - DHEAD)) * NPAD + n] = hv;
    }
  }
}

// ---------------------------------------------------------------------------
// Attention over the 1000-entry table with log-count bias.
// Block: 4 waves x 32 q-rows = 128 rows of one (b,h). 16 key tiles of 64.
// K/V staged via global_load_lds w/ XOR-swizzled source + swizzled reads.
// ---------------------------------------------------------------------------
__global__ __launch_bounds__(256) void attn_table(const __bf16* __restrict__ qph,
                                                  const __bf16* __restrict__ Ktab,
                                                  const __bf16* __restrict__ VtT,
                                                  const float* __restrict__ lc,
                                                  __bf16* __restrict__ attn_bf) {
  __shared__ char sK[8192];          // K tile [64 key][64 d] bf16, swizzled slots
  __shared__ char sV[8192];          // V^T tile [64 d][64 key] bf16, swizzled slots
  __shared__ __bf16 sP[4][32][72];   // per-wave P [qrow][key], padded stride
  const int t = threadIdx.x;
  const int wq = t >> 6, lane = t & 63, l15 = lane & 15, g = lane >> 4;
  const int b = blockIdx.z, h = blockIdx.y;
  const int q0 = blockIdx.x * 128 + wq * 32;

  // Q fragments (A: row=l15, k=g*8+j), 2 row-blocks x 2 k-steps
  bf16x8 qa[2][2];
  #pragma unroll
  for (int mi = 0; mi < 2; ++mi)
    #pragma unroll
    for (int ks = 0; ks < 2; ++ks)
      qa[mi][ks] = *(const bf16x8*)&qph[(size_t)(b * SEQ + q0 + mi * 16 + l15) * DIM +
                                        h * DHEAD + ks * 32 + g * 8];

  f32x4 O[2][4];
  #pragma unroll
  for (int mi = 0; mi < 2; ++mi)
    #pragma unroll
    for (int fd = 0; fd < 4; ++fd) O[mi][fd] = (f32x4){0.f, 0.f, 0.f, 0.f};
  float m_[2][4], ls[2][4];
  #pragma unroll
  for (int mi = 0; mi < 2; ++mi)
    #pragma unroll
    for (int r = 0; r < 4; ++r) { m_[mi][r] = -1e30f; ls[mi][r] = 0.f; }

  const __bf16* Kb = Ktab + (size_t)b * NPAD * DHEAD;
  const __bf16* Vb = VtT + (size_t)b * DHEAD * NPAD;
  const float* lcb = lc + b * NPAD;

  for (int n0 = 0; n0 < NPAD; n0 += 64) {
    // stage K (64x64) and V^T (64x64), source-permuted so LDS stays linear
    #pragma unroll
    for (int i = 0; i < 2; ++i) {
      int c = i * 256 + t, row = c >> 3, s = c & 7, sl = s ^ (row & 7);
      GLOAD16(&Kb[(size_t)(n0 + row) * DHEAD + sl * 8], sK + i * 4096 + wq * 1024);
      GLOAD16(&Vb[(size_t)row * NPAD + n0 + sl * 8], sV + i * 4096 + wq * 1024);
    }
    __syncthreads();

    float lcv[4];
    #pragma unroll
    for (int ni = 0; ni < 4; ++ni) lcv[ni] = lcb[n0 + ni * 16 + l15];

    // S = Q K^T  (C/D: col=key=l15, row=q=g*4+r)
    f32x4 S[2][4];
    #pragma unroll
    for (int mi = 0; mi < 2; ++mi)
      #pragma unroll
      for (int ni = 0; ni < 4; ++ni) S[mi][ni] = (f32x4){0.f, 0.f, 0.f, 0.f};
    #pragma unroll
    for (int ks = 0; ks < 2; ++ks) {
      bf16x8 kf[4];
      #pragma unroll
      for (int ni = 0; ni < 4; ++ni)
        kf[ni] = *(const bf16x8*)(sK + (ni * 16 + l15) * 128 +
                                  (((ks * 4 + g) ^ (l15 & 7)) * 16));
      #pragma unroll
      for (int mi = 0; mi < 2; ++mi)
        #pragma unroll
        for (int ni = 0; ni < 4; ++ni)
          S[mi][ni] = mfma16(qa[mi][ks], kf[ni], S[mi][ni]);
    }

    // online softmax with +ln(count) bias; masked keys => p = 0
    float fac[2][4];
    #pragma unroll
    for (int mi = 0; mi < 2; ++mi)
      #pragma unroll
      for (int r = 0; r < 4; ++r) {
        float tv[4];
        #pragma unroll
        for (int ni = 0; ni < 4; ++ni) tv[ni] = S[mi][ni][r] * 0.125f + lcv[ni];
        float tmax = fmaxf(fmaxf(tv[0], tv[1]), fmaxf(tv[2], tv[3]));
        #pragma unroll
        for (int off = 1; off < 16; off <<= 1) tmax = fmaxf(tmax, __shfl_xor(tmax, off));
        float mn = fmaxf(m_[mi][r], tmax);
        float f = __expf(m_[mi][r] - mn);
        m_[mi][r] = mn; fac[mi][r] = f;
        float rs = 0.f;
        #pragma unroll
        for (int ni = 0; ni < 4; ++ni) {
          float p = (tv[ni] > -1e29f) ? __expf(tv[ni] - mn) : 0.f;
          rs += p;
          sP[wq][mi * 16 + g * 4 + r][ni * 16 + l15] = (__bf16)p;
        }
        #pragma unroll
        for (int off = 1; off < 16; off <<= 1) rs += __shfl_xor(rs, off);
        ls[mi][r] = ls[mi][r] * f + rs;
      }
    #pragma unroll
    for (int mi = 0; mi < 2; ++mi)
      #pragma unroll
      for (int fd = 0; fd < 4; ++fd)
        #pragma unroll
        for (int r = 0; r < 4; ++r) O[mi][fd][r] *= fac[mi][r];

    // O += P V   (A=P from per-wave LDS, B=V^T tile; C/D: col=d, row=q)
    #pragma unroll
    for (int mi = 0; mi < 2; ++mi)
      #pragma unroll
      for (int ks = 0; ks < 2; ++ks) {
        bf16x8 pa = *(const bf16x8*)&sP[wq][mi * 16 + l15][ks * 32 + g * 8];
        #pragma unroll
        for (int fd = 0; fd < 4; ++fd) {
          bf16x8 vf = *(const bf16x8*)(sV + (fd * 16 + l15) * 128 +
                                       (((ks * 4 + g) ^ (l15 & 7)) * 16));
          O[mi][fd] = mfma16(pa, vf, O[mi][fd]);
        }
      }
    __syncthreads();
  }

  #pragma unroll
  for (int mi = 0; mi < 2; ++mi)
    #pragma unroll
    for (int r = 0; r < 4; ++r) {
      float inv = 1.f / ls[mi][r];
      size_t row = (size_t)(b * SEQ + q0 + mi * 16 + g * 4 + r);
      #pragma unroll
      for (int fd = 0; fd < 4; ++fd)
        attn_bf[row * DIM + h * DHEAD + fd * 16 + l15] = (__bf16)(O[mi][fd][r] * inv);
    }
}

// ---------------------------------------------------------------------------
// Weight / input casts (verified round 2)
// ---------------------------------------------------------------------------
__global__ __launch_bounds__(256) void cast_w_t(const float* __restrict__ in,
                                                __bf16* __restrict__ oh,
                                                __bf16* __restrict__ ol,
                                                int writeLo) {
  __shared__ float tile[64][65];
  const int t = threadIdx.x;
  const int k0 = blockIdx.x * 64, n0 = blockIdx.y * 64;
  #pragma unroll
  for (int i = 0; i < 16; ++i) {
    int e = t + i * 256, r = e >> 6, c = e & 63;
    tile[r][c] = in[(size_t)(k0 + r) * DIM + n0 + c];
  }
  __syncthreads();
  #pragma unroll
  for (int i = 0; i < 16; ++i) {
    int e = t + i * 256, r = e >> 6, c = e & 63;
    float v = tile[c][r];
    __bf16 h = (__bf16)v;
    oh[(size_t)(n0 + r) * DIM + k0 + c] = h;
    if (writeLo) ol[(size_t)(n0 + r) * DIM + k0 + c] = (__bf16)(v - (float)h);
  }
}

__global__ __launch_bounds__(256) void cast_mem(const float* __restrict__ mem,
                                                __bf16* __restrict__ mh,
                                                __bf16* __restrict__ ml) {
  size_t e = ((size_t)blockIdx.x * 256 + threadIdx.x) * 8;
  int d = (int)(e & 1023);
  size_t rn = e >> 10;
  int n = (int)(rn & 1023), b = (int)(rn >> 10);
  bf16x8 h8, l8;
  if (n < NMEM) {
    const float* p = mem + ((size_t)b * NMEM + n) * DIM + d;
    #pragma unroll
    for (int j = 0; j < 8; ++j) {
      float v = p[j];
      __bf16 h = (__bf16)v;
      h8[j] = h; l8[j] = (__bf16)(v - (float)h);
    }
  } else {
    #pragma unroll
    for (int j = 0; j < 8; ++j) { h8[j] = (__bf16)0.f; l8[j] = (__bf16)0.f; }
  }
  *(bf16x8*)(mh + e) = h8;
  *(bf16x8*)(ml + e) = l8;
}

// ---------------------------------------------------------------------------
extern "C" void kernel_launch(void* const* d_in, const int* in_sizes, int n_in,
                              void* d_out, int out_size, void* d_ws, size_t ws_size,
                              hipStream_t stream) {
  const float* q        = (const float*)d_in[0];
  const float* mem      = (const float*)d_in[2];
  const float* w_q      = (const float*)d_in[3];
  const float* w_kv     = (const float*)d_in[4];
  const float* w_concat = (const float*)d_in[5];
  float* out = (float*)d_out;

  char* wsb = (char*)d_ws;
  __bf16* memh  = (__bf16*)(wsb + 0);                  //  8 MiB
  __bf16* meml  = (__bf16*)(wsb + 8388608);            //  8 MiB
  __bf16* wqt_h = (__bf16*)(wsb + 16777216);           //  2 MiB
  __bf16* wqt_l = (__bf16*)(wsb + 18874368);           //  2 MiB
  __bf16* wct   = (__bf16*)(wsb + 20971520);           //  2 MiB
  __bf16* Ktab  = (__bf16*)(wsb + 23068672);           //  512 KiB
  __bf16* VtT   = (__bf16*)(wsb + 23592960);           //  512 KiB
  float*  lc    = (float*) (wsb + 24117248);           //  16 KiB
  float*  pv    = (float*) (wsb + 24133632);           //  256 KiB
  int*    pi    = (int*)   (wsb + 24395776);           //  256 KiB
  int*    idx   = (int*)   (wsb + 24657920);           //  32 KiB
  __bf16* qph   = (__bf16*)(wsb + 24690688);           // 16 MiB
  __bf16* qpl   = (__bf16*)(wsb + 41467904);           // 16 MiB (reused as attn_bf)
  __bf16* attn_bf = qpl;

  cast_w_t<<<dim3(16, 16), 256, 0, stream>>>(w_q, wqt_h, wqt_l, 1);
  cast_w_t<<<dim3(16, 16), 256, 0, stream>>>(w_concat, wct, (__bf16*)0, 0);
  cast_mem<<<dim3(2048), 256, 0, stream>>>(mem, memh, meml);

  // qp = q @ w_q -> qph/qpl
  gemm3<1, 3, MODE_HILO><<<dim3(64, 8, 1), 256, 32768, stream>>>(
      (const void*)q, (const __bf16*)0, wqt_h, wqt_l, 0, 0,
      (float*)0, qph, qpl, (float*)0, (int*)0);

  // kNN scores + argmax partials
  gemm3<0, 3, MODE_ARGMAX><<<dim3(16, 8, 4), 256, 32768, stream>>>(
      (const void*)qph, qpl, memh, meml, 2048, (long)NPAD * DIM,
      (float*)0, (__bf16*)0, (__bf16*)0, pv, pi);
  knn_reduce<<<dim3(32), 256, 0, stream>>>(pv, pi, idx);

  // counts -> log bias; K/V tables over all 1000 memories
  hist_lc<<<dim3(BATCH), 256, 0, stream>>>(idx, lc);
  table_gemm<<<dim3(BATCH * NPAD / 64), 256, 0, stream>>>(mem, w_kv, Ktab, VtT);

  // attention over the table
  attn_table<<<dim3(SEQ / 128, NHEAD, BATCH), 256, 0, stream>>>(qph, Ktab, VtT, lc, attn_bf);

  // out = attn @ w_concat
  gemm3<0, 1, MODE_C><<<dim3(64, 8, 1), 256, 16384, stream>>>(
      (const void*)attn_bf, (const __bf16*)0, wct, (const __bf16*)0, 0, 0,
      out, (__bf16*)0, (__bf16*)0, (float*)0, (int*)0);
}

// Round 4
// 324.326 us; speedup vs baseline: 6.4853x; 1.2691x over previous
//
#include <hip/hip_runtime.h>
#include <float.h>
#include <math.h>

// KNNAttention: b=4, l=2048, d=1024, h=16, dh=64, n_mem=1000
#define BATCH 4
#define SEQ   2048
#define DIM   1024
#define NHEAD 16
#define DHEAD 64
#define NMEM  1000
#define NPAD  1024          // padded memory slots
#define ROWS  (BATCH*SEQ)   // 8192

typedef __attribute__((ext_vector_type(8))) __bf16 bf16x8;
typedef __attribute__((ext_vector_type(4))) float  f32x4;

static __device__ inline f32x4 mfma16(bf16x8 a, bf16x8 b, f32x4 c) {
  return __builtin_amdgcn_mfma_f32_16x16x32_bf16(a, b, c, 0, 0, 0);
}

// async global->LDS, 16B per lane. LDS dest must be wave-uniform base (+lane*16).
#define GLOAD16(g, l) __builtin_amdgcn_global_load_lds( \
    (const __attribute__((address_space(1))) unsigned int*)(g), \
    (__attribute__((address_space(3))) unsigned int*)(l), 16, 0, 0)

enum { MODE_C = 0, MODE_HILO = 1, MODE_ARGMAX = 2, MODE_KV = 3 };

// ---------------------------------------------------------------------------
// Fused split-bf16 GEMM (verified rounds 2-3): C = A * B^T, up to 3 products.
// MODE_KV: N=128 fixed; cols 0-63 -> Ktab row-major (Oh), cols 64-127 ->
// VtT transposed [b][d][n] (Ol). Rows are b*NPAD+n (padded mem slots).
// ---------------------------------------------------------------------------
template<int AF32, int NPROD, int MODE>
__global__ __launch_bounds__(256) void gemm3(
    const void* __restrict__ Ah_, const __bf16* __restrict__ Al,
    const __bf16* __restrict__ Bh, const __bf16* __restrict__ Bl,
    int rowsPerZ, long bStrideZ,
    float* __restrict__ C, __bf16* __restrict__ Oh, __bf16* __restrict__ Ol,
    float* __restrict__ pv, int* __restrict__ pi)
{
  extern __shared__ char smem[];
  __shared__ float s_pv[128];
  __shared__ int   s_pi[128];
  const int t = threadIdx.x;
  const int w = t >> 6, lane = t & 63, l15 = lane & 15, g = lane >> 4;
  const int wr = w >> 1, wc = w & 1;
  const int m0 = blockIdx.z * rowsPerZ + blockIdx.x * 128;
  const int n0 = blockIdx.y * 128;
  const __bf16* Bh_b = Bh + (size_t)blockIdx.z * bStrideZ;
  const __bf16* Bl_b = (NPROD == 3) ? (Bl + (size_t)blockIdx.z * bStrideZ) : (const __bf16*)0;

  char* sA  = smem;
  char* sAl = smem + 8192;
  char* sBh = smem + (AF32 ? 16384 : (NPROD == 3 ? 16384 : 8192));
  char* sBl = sBh + 8192;

  f32x4 acc[4][4];
  #pragma unroll
  for (int i = 0; i < 4; ++i)
    #pragma unroll
    for (int j = 0; j < 4; ++j) acc[i][j] = (f32x4){0.f, 0.f, 0.f, 0.f};

  for (int k0 = 0; k0 < DIM; k0 += 32) {
    if (AF32) {
      const float* Af = (const float*)Ah_;
      #pragma unroll
      for (int i = 0; i < 4; ++i) {
        int c = i * 256 + t;
        int r = c >> 3, s = c & 7;
        int sl = s ^ (r & 7);
        GLOAD16(&Af[(size_t)(m0 + r) * DIM + k0 + sl * 4], sA + i * 4096 + w * 1024);
      }
    } else {
      const __bf16* Ab = (const __bf16*)Ah_;
      #pragma unroll
      for (int i = 0; i < 2; ++i) {
        int c = i * 256 + t;
        int r = c >> 2, s = c & 3;
        int sl = s ^ (r & 3);
        GLOAD16(&Ab[(size_t)(m0 + r) * DIM + k0 + sl * 8], sA + i * 4096 + w * 1024);
        if (NPROD == 3)
          GLOAD16(&Al[(size_t)(m0 + r) * DIM + k0 + sl * 8], sAl + i * 4096 + w * 1024);
      }
    }
    #pragma unroll
    for (int i = 0; i < 2; ++i) {
      int c = i * 256 + t;
      int r = c >> 2, s = c & 3;
      int sl = s ^ (r & 3);
      GLOAD16(&Bh_b[(size_t)(n0 + r) * DIM + k0 + sl * 8], sBh + i * 4096 + w * 1024);
      if (NPROD == 3)
        GLOAD16(&Bl_b[(size_t)(n0 + r) * DIM + k0 + sl * 8], sBl + i * 4096 + w * 1024);
    }
    __syncthreads();

    bf16x8 ah[4], al[4], bh[4], bl[4];
    #pragma unroll
    for (int mi = 0; mi < 4; ++mi) {
      int r = wr * 64 + mi * 16 + l15;
      if (AF32) {
        int p0 = (2 * g) ^ (r & 7), p1 = (2 * g + 1) ^ (r & 7);
        float4 q0 = *(const float4*)(sA + r * 128 + p0 * 16);
        float4 q1 = *(const float4*)(sA + r * 128 + p1 * 16);
        float qq[8] = {q0.x, q0.y, q0.z, q0.w, q1.x, q1.y, q1.z, q1.w};
        #pragma unroll
        for (int j = 0; j < 8; ++j) {
          __bf16 h = (__bf16)qq[j];
          ah[mi][j] = h;
          al[mi][j] = (__bf16)(qq[j] - (float)h);
        }
      } else {
        int p = (g ^ (r & 3)) * 16;
        ah[mi] = *(const bf16x8*)(sA + r * 64 + p);
        if (NPROD == 3) al[mi] = *(const bf16x8*)(sAl + r * 64 + p);
      }
    }
    #pragma unroll
    for (int ni = 0; ni < 4; ++ni) {
      int r = wc * 64 + ni * 16 + l15;
      int p = (g ^ (r & 3)) * 16;
      bh[ni] = *(const bf16x8*)(sBh + r * 64 + p);
      if (NPROD == 3) bl[ni] = *(const bf16x8*)(sBl + r * 64 + p);
    }
    #pragma unroll
    for (int mi = 0; mi < 4; ++mi)
      #pragma unroll
      for (int ni = 0; ni < 4; ++ni) {
        acc[mi][ni] = mfma16(ah[mi], bh[ni], acc[mi][ni]);
        if (NPROD == 3) {
          acc[mi][ni] = mfma16(ah[mi], bl[ni], acc[mi][ni]);
          acc[mi][ni] = mfma16(al[mi], bh[ni], acc[mi][ni]);
        }
      }
    __syncthreads();
  }

  if (MODE == MODE_C) {
    #pragma unroll
    for (int mi = 0; mi < 4; ++mi)
      #pragma unroll
      for (int ni = 0; ni < 4; ++ni) {
        int col = n0 + wc * 64 + ni * 16 + l15;
        #pragma unroll
        for (int r = 0; r < 4; ++r) {
          int row = m0 + wr * 64 + mi * 16 + g * 4 + r;
          C[(size_t)row * DIM + col] = acc[mi][ni][r];
        }
      }
  } else if (MODE == MODE_HILO) {
    #pragma unroll
    for (int mi = 0; mi < 4; ++mi)
      #pragma unroll
      for (int ni = 0; ni < 4; ++ni) {
        int col = n0 + wc * 64 + ni * 16 + l15;
        #pragma unroll
        for (int r = 0; r < 4; ++r) {
          int row = m0 + wr * 64 + mi * 16 + g * 4 + r;
          float v = acc[mi][ni][r];
          __bf16 h = (__bf16)v;
          Oh[(size_t)row * DIM + col] = h;
          Ol[(size_t)row * DIM + col] = (__bf16)(v - (float)h);
        }
      }
  } else if (MODE == MODE_KV) {
    // Oh = Ktab [b*NPAD+n][64], Ol = VtT [b][64][NPAD]
    #pragma unroll
    for (int mi = 0; mi < 4; ++mi)
      #pragma unroll
      for (int ni = 0; ni < 4; ++ni) {
        int col = wc * 64 + ni * 16 + l15;
        #pragma unroll
        for (int r = 0; r < 4; ++r) {
          int gr = m0 + wr * 64 + mi * 16 + g * 4 + r;
          int bb = gr >> 10, n = gr & (NPAD - 1);
          __bf16 h = (__bf16)acc[mi][ni][r];
          if (col < DHEAD) Oh[(size_t)gr * DHEAD + col] = h;
          else             Ol[((size_t)bb * DHEAD + (col - DHEAD)) * NPAD + n] = h;
        }
      }
  } else {  // MODE_ARGMAX
    float vv[4][4]; int ii[4][4];
    #pragma unroll
    for (int mi = 0; mi < 4; ++mi)
      #pragma unroll
      for (int r = 0; r < 4; ++r) {
        float v = -FLT_MAX; int vi = 0x7fffffff;
        #pragma unroll
        for (int ni = 0; ni < 4; ++ni) {
          int col = n0 + wc * 64 + ni * 16 + l15;
          float s = (col < NMEM) ? acc[mi][ni][r] : -FLT_MAX;
          if (s > v) { v = s; vi = col; }
        }
        #pragma unroll
        for (int off = 1; off < 16; off <<= 1) {
          float ov = __shfl_xor(v, off);
          int   oi = __shfl_xor(vi, off);
          if (ov > v || (ov == v && oi < vi)) { v = ov; vi = oi; }
        }
        vv[mi][r] = v; ii[mi][r] = vi;
        if (wc == 0 && l15 == 0) {
          int lrow = wr * 64 + mi * 16 + g * 4 + r;
          s_pv[lrow] = v; s_pi[lrow] = vi;
        }
      }
    __syncthreads();
    if (wc == 1 && l15 == 0) {
      #pragma unroll
      for (int mi = 0; mi < 4; ++mi)
        #pragma unroll
        for (int r = 0; r < 4; ++r) {
          int lrow = wr * 64 + mi * 16 + g * 4 + r;
          float v0 = s_pv[lrow]; int i0 = s_pi[lrow];
          float v1 = vv[mi][r];  int i1 = ii[mi][r];
          float v; int vi;
          if (v1 > v0) { v = v1; vi = i1; } else { v = v0; vi = i0; }
          pv[(size_t)blockIdx.y * ROWS + m0 + lrow] = v;
          pi[(size_t)blockIdx.y * ROWS + m0 + lrow] = vi;
        }
    }
  }
}

__global__ __launch_bounds__(256) void knn_reduce(const float* __restrict__ pv,
                                                  const int* __restrict__ pi,
                                                  int* __restrict__ idx) {
  int r = blockIdx.x * 256 + threadIdx.x;
  float bv = -FLT_MAX; int bi = 0x7fffffff;
  #pragma unroll
  for (int c = 0; c < 8; ++c) {
    float v = pv[(size_t)c * ROWS + r];
    int   i = pi[(size_t)c * ROWS + r];
    if (v > bv || (v == bv && i < bi)) { bv = v; bi = i; }
  }
  idx[r] = bi;
}

// ---------------------------------------------------------------------------
// Per-batch histogram of idx -> log-count bias (masked slots = -1e30).
// ---------------------------------------------------------------------------
__global__ __launch_bounds__(256) void hist_lc(const int* __restrict__ idx,
                                               float* __restrict__ lc) {
  __shared__ int hcnt[NPAD];
  const int t = threadIdx.x, b = blockIdx.x;
  #pragma unroll
  for (int i = 0; i < 4; ++i) hcnt[t + 256 * i] = 0;
  __syncthreads();
  #pragma unroll
  for (int i = 0; i < 8; ++i) atomicAdd(&hcnt[idx[b * SEQ + i * 256 + t]], 1);
  __syncthreads();
  #pragma unroll
  for (int i = 0; i < 4; ++i) {
    int n = t + 256 * i;
    int c = hcnt[n];
    lc[b * NPAD + n] = (n < NMEM && c > 0) ? logf((float)c) : -1e30f;
  }
}

// ---------------------------------------------------------------------------
// Attention over the 1000-entry table with log-count bias (verified round 3).
// ---------------------------------------------------------------------------
__global__ __launch_bounds__(256) void attn_table(const __bf16* __restrict__ qph,
                                                  const __bf16* __restrict__ Ktab,
                                                  const __bf16* __restrict__ VtT,
                                                  const float* __restrict__ lc,
                                                  __bf16* __restrict__ attn_bf) {
  __shared__ char sK[8192];
  __shared__ char sV[8192];
  __shared__ __bf16 sP[4][32][72];
  const int t = threadIdx.x;
  const int wq = t >> 6, lane = t & 63, l15 = lane & 15, g = lane >> 4;
  const int b = blockIdx.z, h = blockIdx.y;
  const int q0 = blockIdx.x * 128 + wq * 32;

  bf16x8 qa[2][2];
  #pragma unroll
  for (int mi = 0; mi < 2; ++mi)
    #pragma unroll
    for (int ks = 0; ks < 2; ++ks)
      qa[mi][ks] = *(const bf16x8*)&qph[(size_t)(b * SEQ + q0 + mi * 16 + l15) * DIM +
                                        h * DHEAD + ks * 32 + g * 8];

  f32x4 O[2][4];
  #pragma unroll
  for (int mi = 0; mi < 2; ++mi)
    #pragma unroll
    for (int fd = 0; fd < 4; ++fd) O[mi][fd] = (f32x4){0.f, 0.f, 0.f, 0.f};
  float m_[2][4], ls[2][4];
  #pragma unroll
  for (int mi = 0; mi < 2; ++mi)
    #pragma unroll
    for (int r = 0; r < 4; ++r) { m_[mi][r] = -1e30f; ls[mi][r] = 0.f; }

  const __bf16* Kb = Ktab + (size_t)b * NPAD * DHEAD;
  const __bf16* Vb = VtT + (size_t)b * DHEAD * NPAD;
  const float* lcb = lc + b * NPAD;

  for (int n0 = 0; n0 < NPAD; n0 += 64) {
    #pragma unroll
    for (int i = 0; i < 2; ++i) {
      int c = i * 256 + t, row = c >> 3, s = c & 7, sl = s ^ (row & 7);
      GLOAD16(&Kb[(size_t)(n0 + row) * DHEAD + sl * 8], sK + i * 4096 + wq * 1024);
      GLOAD16(&Vb[(size_t)row * NPAD + n0 + sl * 8], sV + i * 4096 + wq * 1024);
    }
    __syncthreads();

    float lcv[4];
    #pragma unroll
    for (int ni = 0; ni < 4; ++ni) lcv[ni] = lcb[n0 + ni * 16 + l15];

    f32x4 S[2][4];
    #pragma unroll
    for (int mi = 0; mi < 2; ++mi)
      #pragma unroll
      for (int ni = 0; ni < 4; ++ni) S[mi][ni] = (f32x4){0.f, 0.f, 0.f, 0.f};
    #pragma unroll
    for (int ks = 0; ks < 2; ++ks) {
      bf16x8 kf[4];
      #pragma unroll
      for (int ni = 0; ni < 4; ++ni)
        kf[ni] = *(const bf16x8*)(sK + (ni * 16 + l15) * 128 +
                                  (((ks * 4 + g) ^ (l15 & 7)) * 16));
      #pragma unroll
      for (int mi = 0; mi < 2; ++mi)
        #pragma unroll
        for (int ni = 0; ni < 4; ++ni)
          S[mi][ni] = mfma16(qa[mi][ks], kf[ni], S[mi][ni]);
    }

    float fac[2][4];
    #pragma unroll
    for (int mi = 0; mi < 2; ++mi)
      #pragma unroll
      for (int r = 0; r < 4; ++r) {
        float tv[4];
        #pragma unroll
        for (int ni = 0; ni < 4; ++ni) tv[ni] = S[mi][ni][r] * 0.125f + lcv[ni];
        float tmax = fmaxf(fmaxf(tv[0], tv[1]), fmaxf(tv[2], tv[3]));
        #pragma unroll
        for (int off = 1; off < 16; off <<= 1) tmax = fmaxf(tmax, __shfl_xor(tmax, off));
        float mn = fmaxf(m_[mi][r], tmax);
        float f = __expf(m_[mi][r] - mn);
        m_[mi][r] = mn; fac[mi][r] = f;
        float rs = 0.f;
        #pragma unroll
        for (int ni = 0; ni < 4; ++ni) {
          float p = (tv[ni] > -1e29f) ? __expf(tv[ni] - mn) : 0.f;
          rs += p;
          sP[wq][mi * 16 + g * 4 + r][ni * 16 + l15] = (__bf16)p;
        }
        #pragma unroll
        for (int off = 1; off < 16; off <<= 1) rs += __shfl_xor(rs, off);
        ls[mi][r] = ls[mi][r] * f + rs;
      }
    #pragma unroll
    for (int mi = 0; mi < 2; ++mi)
      #pragma unroll
      for (int fd = 0; fd < 4; ++fd)
        #pragma unroll
        for (int r = 0; r < 4; ++r) O[mi][fd][r] *= fac[mi][r];

    #pragma unroll
    for (int mi = 0; mi < 2; ++mi)
      #pragma unroll
      for (int ks = 0; ks < 2; ++ks) {
        bf16x8 pa = *(const bf16x8*)&sP[wq][mi * 16 + l15][ks * 32 + g * 8];
        #pragma unroll
        for (int fd = 0; fd < 4; ++fd) {
          bf16x8 vf = *(const bf16x8*)(sV + (fd * 16 + l15) * 128 +
                                       (((ks * 4 + g) ^ (l15 & 7)) * 16));
          O[mi][fd] = mfma16(pa, vf, O[mi][fd]);
        }
      }
    __syncthreads();
  }

  #pragma unroll
  for (int mi = 0; mi < 2; ++mi)
    #pragma unroll
    for (int r = 0; r < 4; ++r) {
      float inv = 1.f / ls[mi][r];
      size_t row = (size_t)(b * SEQ + q0 + mi * 16 + g * 4 + r);
      #pragma unroll
      for (int fd = 0; fd < 4; ++fd)
        attn_bf[row * DIM + h * DHEAD + fd * 16 + l15] = (__bf16)(O[mi][fd][r] * inv);
    }
}

// ---------------------------------------------------------------------------
// Casts
// ---------------------------------------------------------------------------
__global__ __launch_bounds__(256) void cast_w_t(const float* __restrict__ in,
                                                __bf16* __restrict__ oh,
                                                __bf16* __restrict__ ol,
                                                int writeLo) {
  __shared__ float tile[64][65];
  const int t = threadIdx.x;
  const int k0 = blockIdx.x * 64, n0 = blockIdx.y * 64;
  #pragma unroll
  for (int i = 0; i < 16; ++i) {
    int e = t + i * 256, r = e >> 6, c = e & 63;
    tile[r][c] = in[(size_t)(k0 + r) * DIM + n0 + c];
  }
  __syncthreads();
  #pragma unroll
  for (int i = 0; i < 16; ++i) {
    int e = t + i * 256, r = e >> 6, c = e & 63;
    float v = tile[c][r];
    __bf16 h = (__bf16)v;
    oh[(size_t)(n0 + r) * DIM + k0 + c] = h;
    if (writeLo) ol[(size_t)(n0 + r) * DIM + k0 + c] = (__bf16)(v - (float)h);
  }
}

// w_kv [1024][128] f32 -> [128][1024] bf16 hi/lo
__global__ __launch_bounds__(256) void cast_wkv_t(const float* __restrict__ in,
                                                  __bf16* __restrict__ oh,
                                                  __bf16* __restrict__ ol) {
  __shared__ float tile[64][65];
  const int t = threadIdx.x;
  const int k0 = blockIdx.x * 64, n0 = blockIdx.y * 64;
  #pragma unroll
  for (int i = 0; i < 16; ++i) {
    int e = t + i * 256, r = e >> 6, c = e & 63;
    tile[r][c] = in[(size_t)(k0 + r) * 128 + n0 + c];
  }
  __syncthreads();
  #pragma unroll
  for (int i = 0; i < 16; ++i) {
    int e = t + i * 256, r = e >> 6, c = e & 63;   // r: n-dir, c: k-dir
    float v = tile[c][r];
    __bf16 h = (__bf16)v;
    oh[(size_t)(n0 + r) * DIM + k0 + c] = h;
    ol[(size_t)(n0 + r) * DIM + k0 + c] = (__bf16)(v - (float)h);
  }
}

__global__ __launch_bounds__(256) void cast_mem(const float* __restrict__ mem,
                                                __bf16* __restrict__ mh,
                                                __bf16* __restrict__ ml) {
  size_t e = ((size_t)blockIdx.x * 256 + threadIdx.x) * 8;
  int d = (int)(e & 1023);
  size_t rn = e >> 10;
  int n = (int)(rn & 1023), b = (int)(rn >> 10);
  bf16x8 h8, l8;
  if (n < NMEM) {
    const float* p = mem + ((size_t)b * NMEM + n) * DIM + d;
    #pragma unroll
    for (int j = 0; j < 8; ++j) {
      float v = p[j];
      __bf16 h = (__bf16)v;
      h8[j] = h; l8[j] = (__bf16)(v - (float)h);
    }
  } else {
    #pragma unroll
    for (int j = 0; j < 8; ++j) { h8[j] = (__bf16)0.f; l8[j] = (__bf16)0.f; }
  }
  *(bf16x8*)(mh + e) = h8;
  *(bf16x8*)(ml + e) = l8;
}

// ---------------------------------------------------------------------------
extern "C" void kernel_launch(void* const* d_in, const int* in_sizes, int n_in,
                              void* d_out, int out_size, void* d_ws, size_t ws_size,
                              hipStream_t stream) {
  const float* q        = (const float*)d_in[0];
  const float* mem      = (const float*)d_in[2];
  const float* w_q      = (const float*)d_in[3];
  const float* w_kv     = (const float*)d_in[4];
  const float* w_concat = (const float*)d_in[5];
  float* out = (float*)d_out;

  char* wsb = (char*)d_ws;
  __bf16* memh   = (__bf16*)(wsb + 0);                  //  8 MiB
  __bf16* meml   = (__bf16*)(wsb + 8388608);            //  8 MiB
  __bf16* wqt_h  = (__bf16*)(wsb + 16777216);           //  2 MiB
  __bf16* wqt_l  = (__bf16*)(wsb + 18874368);           //  2 MiB
  __bf16* wct    = (__bf16*)(wsb + 20971520);           //  2 MiB
  __bf16* Ktab   = (__bf16*)(wsb + 23068672);           //  512 KiB
  __bf16* VtT    = (__bf16*)(wsb + 23592960);           //  512 KiB
  float*  lc     = (float*) (wsb + 24117248);           //  16 KiB
  float*  pv     = (float*) (wsb + 24133632);           //  256 KiB
  int*    pi     = (int*)   (wsb + 24395776);           //  256 KiB
  int*    idx    = (int*)   (wsb + 24657920);           //  32 KiB
  __bf16* wkvT_h = (__bf16*)(wsb + 24690688);           //  256 KiB
  __bf16* wkvT_l = (__bf16*)(wsb + 24952832);           //  256 KiB
  __bf16* qph    = (__bf16*)(wsb + 25214976);           // 16 MiB
  __bf16* qpl    = (__bf16*)(wsb + 41992192);           // 16 MiB (reused as attn_bf)
  __bf16* attn_bf = qpl;

  cast_w_t<<<dim3(16, 16), 256, 0, stream>>>(w_q, wqt_h, wqt_l, 1);
  cast_w_t<<<dim3(16, 16), 256, 0, stream>>>(w_concat, wct, (__bf16*)0, 0);
  cast_wkv_t<<<dim3(16, 2), 256, 0, stream>>>(w_kv, wkvT_h, wkvT_l);
  cast_mem<<<dim3(2048), 256, 0, stream>>>(mem, memh, meml);

  // qp = q @ w_q -> qph/qpl
  gemm3<1, 3, MODE_HILO><<<dim3(64, 8, 1), 256, 32768, stream>>>(
      (const void*)q, (const __bf16*)0, wqt_h, wqt_l, 0, 0,
      (float*)0, qph, qpl, (float*)0, (int*)0);

  // K/V tables over all memories: (memh/meml) @ w_kv^T -> Ktab, VtT
  gemm3<0, 3, MODE_KV><<<dim3(BATCH * NPAD / 128, 1, 1), 256, 32768, stream>>>(
      (const void*)memh, meml, wkvT_h, wkvT_l, 0, 0,
      (float*)0, Ktab, VtT, (float*)0, (int*)0);

  // kNN scores + argmax partials
  gemm3<0, 3, MODE_ARGMAX><<<dim3(16, 8, 4), 256, 32768, stream>>>(
      (const void*)qph, qpl, memh, meml, 2048, (long)NPAD * DIM,
      (float*)0, (__bf16*)0, (__bf16*)0, pv, pi);
  knn_reduce<<<dim3(32), 256, 0, stream>>>(pv, pi, idx);

  // counts -> log bias
  hist_lc<<<dim3(BATCH), 256, 0, stream>>>(idx, lc);

  // attention over the table
  attn_table<<<dim3(SEQ / 128, NHEAD, BATCH), 256, 0, stream>>>(qph, Ktab, VtT, lc, attn_bf);

  // out = attn @ w_concat
  gemm3<0, 1, MODE_C><<<dim3(64, 8, 1), 256, 16384, stream>>>(
      (const void*)attn_bf, (const __bf16*)0, wct, (const __bf16*)0, 0, 0,
      out, (__bf16*)0, (__bf16*)0, (float*)0, (int*)0);
}

// Round 5
// 273.334 us; speedup vs baseline: 7.6952x; 1.1866x over previous
//
#include <hip/hip_runtime.h>
#include <float.h>
#include <math.h>

// KNNAttention: b=4, l=2048, d=1024, h=16, dh=64, n_mem=1000
#define BATCH 4
#define SEQ   2048
#define DIM   1024
#define NHEAD 16
#define DHEAD 64
#define NMEM  1000
#define NPAD  1024          // padded memory slots
#define ROWS  (BATCH*SEQ)   // 8192

typedef __attribute__((ext_vector_type(8))) __bf16 bf16x8;
typedef __attribute__((ext_vector_type(4))) float  f32x4;

static __device__ inline f32x4 mfma16(bf16x8 a, bf16x8 b, f32x4 c) {
  return __builtin_amdgcn_mfma_f32_16x16x32_bf16(a, b, c, 0, 0, 0);
}

// async global->LDS, 16B per lane. LDS dest must be wave-uniform base (+lane*16).
#define GLOAD16(g, l) __builtin_amdgcn_global_load_lds( \
    (const __attribute__((address_space(1))) unsigned int*)(g), \
    (__attribute__((address_space(3))) unsigned int*)(l), 16, 0, 0)

enum { MODE_C = 0, MODE_HILO = 1, MODE_ARGMAX = 2, MODE_KV = 3 };

// ---------------------------------------------------------------------------
// Fused split-bf16 GEMM (verified rounds 2-4): C = A * B^T, up to 3 products.
// ---------------------------------------------------------------------------
template<int AF32, int NPROD, int MODE>
__global__ __launch_bounds__(256) void gemm3(
    const void* __restrict__ Ah_, const __bf16* __restrict__ Al,
    const __bf16* __restrict__ Bh, const __bf16* __restrict__ Bl,
    int rowsPerZ, long bStrideZ,
    float* __restrict__ C, __bf16* __restrict__ Oh, __bf16* __restrict__ Ol,
    float* __restrict__ pv, int* __restrict__ pi)
{
  extern __shared__ char smem[];
  __shared__ float s_pv[128];
  __shared__ int   s_pi[128];
  const int t = threadIdx.x;
  const int w = t >> 6, lane = t & 63, l15 = lane & 15, g = lane >> 4;
  const int wr = w >> 1, wc = w & 1;
  const int m0 = blockIdx.z * rowsPerZ + blockIdx.x * 128;
  const int n0 = blockIdx.y * 128;
  const __bf16* Bh_b = Bh + (size_t)blockIdx.z * bStrideZ;
  const __bf16* Bl_b = (NPROD == 3) ? (Bl + (size_t)blockIdx.z * bStrideZ) : (const __bf16*)0;

  char* sA  = smem;
  char* sAl = smem + 8192;
  char* sBh = smem + (AF32 ? 16384 : (NPROD == 3 ? 16384 : 8192));
  char* sBl = sBh + 8192;

  f32x4 acc[4][4];
  #pragma unroll
  for (int i = 0; i < 4; ++i)
    #pragma unroll
    for (int j = 0; j < 4; ++j) acc[i][j] = (f32x4){0.f, 0.f, 0.f, 0.f};

  for (int k0 = 0; k0 < DIM; k0 += 32) {
    if (AF32) {
      const float* Af = (const float*)Ah_;
      #pragma unroll
      for (int i = 0; i < 4; ++i) {
        int c = i * 256 + t;
        int r = c >> 3, s = c & 7;
        int sl = s ^ (r & 7);
        GLOAD16(&Af[(size_t)(m0 + r) * DIM + k0 + sl * 4], sA + i * 4096 + w * 1024);
      }
    } else {
      const __bf16* Ab = (const __bf16*)Ah_;
      #pragma unroll
      for (int i = 0; i < 2; ++i) {
        int c = i * 256 + t;
        int r = c >> 2, s = c & 3;
        int sl = s ^ (r & 3);
        GLOAD16(&Ab[(size_t)(m0 + r) * DIM + k0 + sl * 8], sA + i * 4096 + w * 1024);
        if (NPROD == 3)
          GLOAD16(&Al[(size_t)(m0 + r) * DIM + k0 + sl * 8], sAl + i * 4096 + w * 1024);
      }
    }
    #pragma unroll
    for (int i = 0; i < 2; ++i) {
      int c = i * 256 + t;
      int r = c >> 2, s = c & 3;
      int sl = s ^ (r & 3);
      GLOAD16(&Bh_b[(size_t)(n0 + r) * DIM + k0 + sl * 8], sBh + i * 4096 + w * 1024);
      if (NPROD == 3)
        GLOAD16(&Bl_b[(size_t)(n0 + r) * DIM + k0 + sl * 8], sBl + i * 4096 + w * 1024);
    }
    __syncthreads();

    bf16x8 ah[4], al[4], bh[4], bl[4];
    #pragma unroll
    for (int mi = 0; mi < 4; ++mi) {
      int r = wr * 64 + mi * 16 + l15;
      if (AF32) {
        int p0 = (2 * g) ^ (r & 7), p1 = (2 * g + 1) ^ (r & 7);
        float4 q0 = *(const float4*)(sA + r * 128 + p0 * 16);
        float4 q1 = *(const float4*)(sA + r * 128 + p1 * 16);
        float qq[8] = {q0.x, q0.y, q0.z, q0.w, q1.x, q1.y, q1.z, q1.w};
        #pragma unroll
        for (int j = 0; j < 8; ++j) {
          __bf16 h = (__bf16)qq[j];
          ah[mi][j] = h;
          al[mi][j] = (__bf16)(qq[j] - (float)h);
        }
      } else {
        int p = (g ^ (r & 3)) * 16;
        ah[mi] = *(const bf16x8*)(sA + r * 64 + p);
        if (NPROD == 3) al[mi] = *(const bf16x8*)(sAl + r * 64 + p);
      }
    }
    #pragma unroll
    for (int ni = 0; ni < 4; ++ni) {
      int r = wc * 64 + ni * 16 + l15;
      int p = (g ^ (r & 3)) * 16;
      bh[ni] = *(const bf16x8*)(sBh + r * 64 + p);
      if (NPROD == 3) bl[ni] = *(const bf16x8*)(sBl + r * 64 + p);
    }
    #pragma unroll
    for (int mi = 0; mi < 4; ++mi)
      #pragma unroll
      for (int ni = 0; ni < 4; ++ni) {
        acc[mi][ni] = mfma16(ah[mi], bh[ni], acc[mi][ni]);
        if (NPROD == 3) {
          acc[mi][ni] = mfma16(ah[mi], bl[ni], acc[mi][ni]);
          acc[mi][ni] = mfma16(al[mi], bh[ni], acc[mi][ni]);
        }
      }
    __syncthreads();
  }

  if (MODE == MODE_C) {
    #pragma unroll
    for (int mi = 0; mi < 4; ++mi)
      #pragma unroll
      for (int ni = 0; ni < 4; ++ni) {
        int col = n0 + wc * 64 + ni * 16 + l15;
        #pragma unroll
        for (int r = 0; r < 4; ++r) {
          int row = m0 + wr * 64 + mi * 16 + g * 4 + r;
          C[(size_t)row * DIM + col] = acc[mi][ni][r];
        }
      }
  } else if (MODE == MODE_HILO) {
    #pragma unroll
    for (int mi = 0; mi < 4; ++mi)
      #pragma unroll
      for (int ni = 0; ni < 4; ++ni) {
        int col = n0 + wc * 64 + ni * 16 + l15;
        #pragma unroll
        for (int r = 0; r < 4; ++r) {
          int row = m0 + wr * 64 + mi * 16 + g * 4 + r;
          float v = acc[mi][ni][r];
          __bf16 h = (__bf16)v;
          Oh[(size_t)row * DIM + col] = h;
          Ol[(size_t)row * DIM + col] = (__bf16)(v - (float)h);
        }
      }
  } else if (MODE == MODE_KV) {
    // Oh = Ktab [b*NPAD+n][64], Ol = VtT [b][64][NPAD]
    #pragma unroll
    for (int mi = 0; mi < 4; ++mi)
      #pragma unroll
      for (int ni = 0; ni < 4; ++ni) {
        int col = wc * 64 + ni * 16 + l15;
        #pragma unroll
        for (int r = 0; r < 4; ++r) {
          int gr = m0 + wr * 64 + mi * 16 + g * 4 + r;
          int bb = gr >> 10, n = gr & (NPAD - 1);
          __bf16 h = (__bf16)acc[mi][ni][r];
          if (col < DHEAD) Oh[(size_t)gr * DHEAD + col] = h;
          else             Ol[((size_t)bb * DHEAD + (col - DHEAD)) * NPAD + n] = h;
        }
      }
  } else {  // MODE_ARGMAX
    float vv[4][4]; int ii[4][4];
    #pragma unroll
    for (int mi = 0; mi < 4; ++mi)
      #pragma unroll
      for (int r = 0; r < 4; ++r) {
        float v = -FLT_MAX; int vi = 0x7fffffff;
        #pragma unroll
        for (int ni = 0; ni < 4; ++ni) {
          int col = n0 + wc * 64 + ni * 16 + l15;
          float s = (col < NMEM) ? acc[mi][ni][r] : -FLT_MAX;
          if (s > v) { v = s; vi = col; }
        }
        #pragma unroll
        for (int off = 1; off < 16; off <<= 1) {
          float ov = __shfl_xor(v, off);
          int   oi = __shfl_xor(vi, off);
          if (ov > v || (ov == v && oi < vi)) { v = ov; vi = oi; }
        }
        vv[mi][r] = v; ii[mi][r] = vi;
        if (wc == 0 && l15 == 0) {
          int lrow = wr * 64 + mi * 16 + g * 4 + r;
          s_pv[lrow] = v; s_pi[lrow] = vi;
        }
      }
    __syncthreads();
    if (wc == 1 && l15 == 0) {
      #pragma unroll
      for (int mi = 0; mi < 4; ++mi)
        #pragma unroll
        for (int r = 0; r < 4; ++r) {
          int lrow = wr * 64 + mi * 16 + g * 4 + r;
          float v0 = s_pv[lrow]; int i0 = s_pi[lrow];
          float v1 = vv[mi][r];  int i1 = ii[mi][r];
          float v; int vi;
          if (v1 > v0) { v = v1; vi = i1; } else { v = v0; vi = i0; }
          pv[(size_t)blockIdx.y * ROWS + m0 + lrow] = v;
          pi[(size_t)blockIdx.y * ROWS + m0 + lrow] = vi;
        }
    }
  }
}

__global__ __launch_bounds__(256) void knn_reduce(const float* __restrict__ pv,
                                                  const int* __restrict__ pi,
                                                  int* __restrict__ idx) {
  int r = blockIdx.x * 256 + threadIdx.x;
  float bv = -FLT_MAX; int bi = 0x7fffffff;
  #pragma unroll
  for (int c = 0; c < 8; ++c) {
    float v = pv[(size_t)c * ROWS + r];
    int   i = pi[(size_t)c * ROWS + r];
    if (v > bv || (v == bv && i < bi)) { bv = v; bi = i; }
  }
  idx[r] = bi;
}

// ---------------------------------------------------------------------------
// Per-batch histogram of idx -> log-count bias (masked slots = -1e30).
// ---------------------------------------------------------------------------
__global__ __launch_bounds__(256) void hist_lc(const int* __restrict__ idx,
                                               float* __restrict__ lc) {
  __shared__ int hcnt[NPAD];
  const int t = threadIdx.x, b = blockIdx.x;
  #pragma unroll
  for (int i = 0; i < 4; ++i) hcnt[t + 256 * i] = 0;
  __syncthreads();
  #pragma unroll
  for (int i = 0; i < 8; ++i) atomicAdd(&hcnt[idx[b * SEQ + i * 256 + t]], 1);
  __syncthreads();
  #pragma unroll
  for (int i = 0; i < 4; ++i) {
    int n = t + 256 * i;
    int c = hcnt[n];
    lc[b * NPAD + n] = (n < NMEM && c > 0) ? logf((float)c) : -1e30f;
  }
}

// ---------------------------------------------------------------------------
// Attention over the 1000-entry table, STATIC softmax (no online max):
// logits bounded (|S|*0.125 <~ 3, lc <= ln(2048)) so exp() cannot overflow;
// masked slots: exp(-1e30) underflows to exactly 0. Per-lane partial sums,
// one 16-lane reduction in the epilogue. sP is per-wave (no barrier needed
// between P-write and PV read; in-wave lgkmcnt ordering suffices).
// ---------------------------------------------------------------------------
__global__ __launch_bounds__(256) void attn_table(const __bf16* __restrict__ qph,
                                                  const __bf16* __restrict__ Ktab,
                                                  const __bf16* __restrict__ VtT,
                                                  const float* __restrict__ lc,
                                                  __bf16* __restrict__ attn_bf) {
  __shared__ char sK[8192];
  __shared__ char sV[8192];
  __shared__ __bf16 sP[4][32][72];
  const int t = threadIdx.x;
  const int wq = t >> 6, lane = t & 63, l15 = lane & 15, g = lane >> 4;
  const int b = blockIdx.z, h = blockIdx.y;
  const int q0 = blockIdx.x * 128 + wq * 32;

  bf16x8 qa[2][2];
  #pragma unroll
  for (int mi = 0; mi < 2; ++mi)
    #pragma unroll
    for (int ks = 0; ks < 2; ++ks)
      qa[mi][ks] = *(const bf16x8*)&qph[(size_t)(b * SEQ + q0 + mi * 16 + l15) * DIM +
                                        h * DHEAD + ks * 32 + g * 8];

  f32x4 O[2][4];
  #pragma unroll
  for (int mi = 0; mi < 2; ++mi)
    #pragma unroll
    for (int fd = 0; fd < 4; ++fd) O[mi][fd] = (f32x4){0.f, 0.f, 0.f, 0.f};
  float lsum[2][4];
  #pragma unroll
  for (int mi = 0; mi < 2; ++mi)
    #pragma unroll
    for (int r = 0; r < 4; ++r) lsum[mi][r] = 0.f;

  const __bf16* Kb = Ktab + (size_t)b * NPAD * DHEAD;
  const __bf16* Vb = VtT + (size_t)b * DHEAD * NPAD;
  const float* lcb = lc + b * NPAD;

  for (int n0 = 0; n0 < NPAD; n0 += 64) {
    #pragma unroll
    for (int i = 0; i < 2; ++i) {
      int c = i * 256 + t, row = c >> 3, s = c & 7, sl = s ^ (row & 7);
      GLOAD16(&Kb[(size_t)(n0 + row) * DHEAD + sl * 8], sK + i * 4096 + wq * 1024);
      GLOAD16(&Vb[(size_t)row * NPAD + n0 + sl * 8], sV + i * 4096 + wq * 1024);
    }
    __syncthreads();

    float lcv[4];
    #pragma unroll
    for (int ni = 0; ni < 4; ++ni) lcv[ni] = lcb[n0 + ni * 16 + l15];

    // S = Q K^T  (C/D: col=key=l15, row=q=g*4+r)
    f32x4 S[2][4];
    #pragma unroll
    for (int mi = 0; mi < 2; ++mi)
      #pragma unroll
      for (int ni = 0; ni < 4; ++ni) S[mi][ni] = (f32x4){0.f, 0.f, 0.f, 0.f};
    #pragma unroll
    for (int ks = 0; ks < 2; ++ks) {
      bf16x8 kf[4];
      #pragma unroll
      for (int ni = 0; ni < 4; ++ni)
        kf[ni] = *(const bf16x8*)(sK + (ni * 16 + l15) * 128 +
                                  (((ks * 4 + g) ^ (l15 & 7)) * 16));
      #pragma unroll
      for (int mi = 0; mi < 2; ++mi)
        #pragma unroll
        for (int ni = 0; ni < 4; ++ni)
          S[mi][ni] = mfma16(qa[mi][ks], kf[ni], S[mi][ni]);
    }

    // static softmax: p = exp(S/8 + lc), per-lane partial sums only
    #pragma unroll
    for (int mi = 0; mi < 2; ++mi)
      #pragma unroll
      for (int r = 0; r < 4; ++r) {
        int row = mi * 16 + g * 4 + r;
        float rs = 0.f;
        #pragma unroll
        for (int ni = 0; ni < 4; ++ni) {
          float p = __expf(fmaf(S[mi][ni][r], 0.125f, lcv[ni]));
          rs += p;
          sP[wq][row][ni * 16 + l15] = (__bf16)p;
        }
        lsum[mi][r] += rs;
      }

    // O += P V (unnormalized; sP same-wave, no barrier needed)
    #pragma unroll
    for (int mi = 0; mi < 2; ++mi)
      #pragma unroll
      for (int ks = 0; ks < 2; ++ks) {
        bf16x8 pa = *(const bf16x8*)&sP[wq][mi * 16 + l15][ks * 32 + g * 8];
        #pragma unroll
        for (int fd = 0; fd < 4; ++fd) {
          bf16x8 vf = *(const bf16x8*)(sV + (fd * 16 + l15) * 128 +
                                       (((ks * 4 + g) ^ (l15 & 7)) * 16));
          O[mi][fd] = mfma16(pa, vf, O[mi][fd]);
        }
      }
    __syncthreads();
  }

  #pragma unroll
  for (int mi = 0; mi < 2; ++mi)
    #pragma unroll
    for (int r = 0; r < 4; ++r) {
      float rs = lsum[mi][r];
      #pragma unroll
      for (int off = 1; off < 16; off <<= 1) rs += __shfl_xor(rs, off);
      float inv = 1.f / rs;
      size_t row = (size_t)(b * SEQ + q0 + mi * 16 + g * 4 + r);
      #pragma unroll
      for (int fd = 0; fd < 4; ++fd)
        attn_bf[row * DIM + h * DHEAD + fd * 16 + l15] = (__bf16)(O[mi][fd][r] * inv);
    }
}

// ---------------------------------------------------------------------------
// Casts
// ---------------------------------------------------------------------------
__global__ __launch_bounds__(256) void cast_w_t(const float* __restrict__ in,
                                                __bf16* __restrict__ oh,
                                                __bf16* __restrict__ ol,
                                                int writeLo) {
  __shared__ float tile[64][65];
  const int t = threadIdx.x;
  const int k0 = blockIdx.x * 64, n0 = blockIdx.y * 64;
  #pragma unroll
  for (int i = 0; i < 16; ++i) {
    int e = t + i * 256, r = e >> 6, c = e & 63;
    tile[r][c] = in[(size_t)(k0 + r) * DIM + n0 + c];
  }
  __syncthreads();
  #pragma unroll
  for (int i = 0; i < 16; ++i) {
    int e = t + i * 256, r = e >> 6, c = e & 63;
    float v = tile[c][r];
    __bf16 h = (__bf16)v;
    oh[(size_t)(n0 + r) * DIM + k0 + c] = h;
    if (writeLo) ol[(size_t)(n0 + r) * DIM + k0 + c] = (__bf16)(v - (float)h);
  }
}

// w_kv [1024][128] f32 -> [128][1024] bf16 hi/lo
__global__ __launch_bounds__(256) void cast_wkv_t(const float* __restrict__ in,
                                                  __bf16* __restrict__ oh,
                                                  __bf16* __restrict__ ol) {
  __shared__ float tile[64][65];
  const int t = threadIdx.x;
  const int k0 = blockIdx.x * 64, n0 = blockIdx.y * 64;
  #pragma unroll
  for (int i = 0; i < 16; ++i) {
    int e = t + i * 256, r = e >> 6, c = e & 63;
    tile[r][c] = in[(size_t)(k0 + r) * 128 + n0 + c];
  }
  __syncthreads();
  #pragma unroll
  for (int i = 0; i < 16; ++i) {
    int e = t + i * 256, r = e >> 6, c = e & 63;   // r: n-dir, c: k-dir
    float v = tile[c][r];
    __bf16 h = (__bf16)v;
    oh[(size_t)(n0 + r) * DIM + k0 + c] = h;
    ol[(size_t)(n0 + r) * DIM + k0 + c] = (__bf16)(v - (float)h);
  }
}

__global__ __launch_bounds__(256) void cast_mem(const float* __restrict__ mem,
                                                __bf16* __restrict__ mh,
                                                __bf16* __restrict__ ml) {
  size_t e = ((size_t)blockIdx.x * 256 + threadIdx.x) * 8;
  int d = (int)(e & 1023);
  size_t rn = e >> 10;
  int n = (int)(rn & 1023), b = (int)(rn >> 10);
  bf16x8 h8, l8;
  if (n < NMEM) {
    const float* p = mem + ((size_t)b * NMEM + n) * DIM + d;
    #pragma unroll
    for (int j = 0; j < 8; ++j) {
      float v = p[j];
      __bf16 h = (__bf16)v;
      h8[j] = h; l8[j] = (__bf16)(v - (float)h);
    }
  } else {
    #pragma unroll
    for (int j = 0; j < 8; ++j) { h8[j] = (__bf16)0.f; l8[j] = (__bf16)0.f; }
  }
  *(bf16x8*)(mh + e) = h8;
  *(bf16x8*)(ml + e) = l8;
}

// ---------------------------------------------------------------------------
extern "C" void kernel_launch(void* const* d_in, const int* in_sizes, int n_in,
                              void* d_out, int out_size, void* d_ws, size_t ws_size,
                              hipStream_t stream) {
  const float* q        = (const float*)d_in[0];
  const float* mem      = (const float*)d_in[2];
  const float* w_q      = (const float*)d_in[3];
  const float* w_kv     = (const float*)d_in[4];
  const float* w_concat = (const float*)d_in[5];
  float* out = (float*)d_out;

  char* wsb = (char*)d_ws;
  __bf16* memh   = (__bf16*)(wsb + 0);                  //  8 MiB
  __bf16* meml   = (__bf16*)(wsb + 8388608);            //  8 MiB
  __bf16* wqt_h  = (__bf16*)(wsb + 16777216);           //  2 MiB
  __bf16* wqt_l  = (__bf16*)(wsb + 18874368);           //  2 MiB
  __bf16* wct    = (__bf16*)(wsb + 20971520);           //  2 MiB
  __bf16* Ktab   = (__bf16*)(wsb + 23068672);           //  512 KiB
  __bf16* VtT    = (__bf16*)(wsb + 23592960);           //  512 KiB
  float*  lc     = (float*) (wsb + 24117248);           //  16 KiB
  float*  pv     = (float*) (wsb + 24133632);           //  256 KiB
  int*    pi     = (int*)   (wsb + 24395776);           //  256 KiB
  int*    idx    = (int*)   (wsb + 24657920);           //  32 KiB
  __bf16* wkvT_h = (__bf16*)(wsb + 24690688);           //  256 KiB
  __bf16* wkvT_l = (__bf16*)(wsb + 24952832);           //  256 KiB
  __bf16* qph    = (__bf16*)(wsb + 25214976);           // 16 MiB
  __bf16* qpl    = (__bf16*)(wsb + 41992192);           // 16 MiB (reused as attn_bf)
  __bf16* attn_bf = qpl;

  cast_w_t<<<dim3(16, 16), 256, 0, stream>>>(w_q, wqt_h, wqt_l, 1);
  cast_w_t<<<dim3(16, 16), 256, 0, stream>>>(w_concat, wct, (__bf16*)0, 0);
  cast_wkv_t<<<dim3(16, 2), 256, 0, stream>>>(w_kv, wkvT_h, wkvT_l);
  cast_mem<<<dim3(2048), 256, 0, stream>>>(mem, memh, meml);

  // qp = q @ w_q -> qph/qpl
  gemm3<1, 3, MODE_HILO><<<dim3(64, 8, 1), 256, 32768, stream>>>(
      (const void*)q, (const __bf16*)0, wqt_h, wqt_l, 0, 0,
      (float*)0, qph, qpl, (float*)0, (int*)0);

  // K/V tables over all memories: (memh/meml) @ w_kv^T -> Ktab, VtT
  gemm3<0, 3, MODE_KV><<<dim3(BATCH * NPAD / 128, 1, 1), 256, 32768, stream>>>(
      (const void*)memh, meml, wkvT_h, wkvT_l, 0, 0,
      (float*)0, Ktab, VtT, (float*)0, (int*)0);

  // kNN scores + argmax partials
  gemm3<0, 3, MODE_ARGMAX><<<dim3(16, 8, 4), 256, 32768, stream>>>(
      (const void*)qph, qpl, memh, meml, 2048, (long)NPAD * DIM,
      (float*)0, (__bf16*)0, (__bf16*)0, pv, pi);
  knn_reduce<<<dim3(32), 256, 0, stream>>>(pv, pi, idx);

  // counts -> log bias
  hist_lc<<<dim3(BATCH), 256, 0, stream>>>(idx, lc);

  // attention over the table
  attn_table<<<dim3(SEQ / 128, NHEAD, BATCH), 256, 0, stream>>>(qph, Ktab, VtT, lc, attn_bf);

  // out = attn @ w_concat
  gemm3<0, 1, MODE_C><<<dim3(64, 8, 1), 256, 16384, stream>>>(
      (const void*)attn_bf, (const __bf16*)0, wct, (const __bf16*)0, 0, 0,
      out, (__bf16*)0, (__bf16*)0, (float*)0, (int*)0);
}